// Round 2
// baseline (407.814 us; speedup 1.0000x reference)
//
#include <hip/hip_runtime.h>
#include <hip/hip_fp16.h>

// GCN 2-layer: N=200000, E=6400000, 14 -> 16(relu) -> 2.
// Round 14: k_agg1 L2-thrash fix. FETCH was 203MB vs ~51MB logical streams:
// the 3.2MB/phase xph gather region got ~no L2 reuse because the csr read
// stream + partial write stream evicted it continuously.
//   - csr loads (agg1/agg2) and partial traffic (agg1 store, mlp load) are now
//     non-temporal (evict-first in L2); xph/h2bp gathers stay cached. L1
//     covers short-term csr line reuse.
//   - agg1 phase = blockIdx&1: under round-robin dispatch phase-0 blocks sit
//     on even XCDs, phase-1 on odd -> each XCD L2 holds ONE 3.2MB phase
//     region for the whole kernel (locality heuristic only, not correctness).
// Pipeline: init -> binA -> sort(+dinv) -> prep -> agg1(2 phase) -> mlp -> agg2.

constexpr int NN = 200000;
constexpr int NE = 6400000;
constexpr int IC = 14;
constexpr int HC = 16;
constexpr int OC = 2;

constexpr int NBK = 392;                   // buckets of 512 dst nodes
constexpr int NSUB = 8;                    // sub-segments per bucket (bid&7)
constexpr int SCAP = 2816;                 // per (sub,bucket) cap: mean 2058 + 16.7 sigma
constexpr int NSEG = NSUB * NBK;           // 3136 segments
constexpr int CCAP = NSUB * SCAP;          // 22528 csr per-bucket capacity
constexpr int TILE = 5120;                 // edges per binA tile
constexpr int IPT = TILE / 256;            // 20
constexpr int IPT2 = IPT / 2;              // 10 pair-loads per thread
constexpr int NTILE = NE / TILE;           // 1250
constexpr int OVFCAP = 65536;
constexpr int NB = (NN + 255) / 256;       // 782
constexpr int NAGG = NN / 64;              // 3125 blocks per phase
constexpr unsigned PHB = 100000u;          // phase boundary on src
constexpr int GSTR = 16;                   // gcur stride: 1 counter per 64B line

typedef unsigned long long ull;
typedef float f4v __attribute__((ext_vector_type(4)));

// init gcur (padded) + ovf counter + dtype flag
__global__ void k_init(int* __restrict__ gcur, const void* __restrict__ ei,
                       int* __restrict__ flag) {
    int i = blockIdx.x * blockDim.x + threadIdx.x;
    if (i < NSEG) gcur[i * GSTR] = i * SCAP;
    else if (i == NSEG) gcur[i * GSTR] = 0;  // overflow counter
    if (i == 500) {  // one thread sniffs edge dtype
        const ull* p = (const ull*)ei;
        ull acc = 0ULL;
        for (int k = 0; k < 64; ++k) acc |= (p[k] >> 32);
        *flag = (acc == 0ULL) ? 1 : 0;  // 1 => int64 indices, 0 => int32
    }
}

// Bin edges by dst>>9 into per-(sub,bucket) global segments, sub = bid&7.
// Rank captured from the histogram atomic; LDS-staged for coalesced segment
// write-out. Bucket of a stage slot recovered by binary search over lofs.
__global__ __launch_bounds__(256, 6) void k_binA(const void* __restrict__ ei,
                                                 const int* __restrict__ flag,
                                                 int* __restrict__ gcur,
                                                 unsigned* __restrict__ binned,
                                                 ull* __restrict__ ovf) {
    __shared__ int hist[NBK];
    __shared__ int lofs[NBK];
    __shared__ int gofs[NBK];
    __shared__ int wsum[4];
    __shared__ unsigned stage[TILE];

    int t = threadIdx.x;
    int fl = *flag;
    int tile0 = blockIdx.x * TILE;
    int segbase = (blockIdx.x & (NSUB - 1)) * NBK;

    if (t < NBK) hist[t] = 0;
    if (t + 256 < NBK) hist[t + 256] = 0;
    __syncthreads();

    // pass 1: dst pairs (16B loads) + rank capture (dr = rank<<18 | dst)
    unsigned dr[IPT];
#pragma unroll
    for (int k = 0; k < IPT2; ++k) {
        int e = tile0 + k * 512 + 2 * t;
        int d0, d1;
        if (fl) {
            ulonglong2 dd = *(const ulonglong2*)((const long long*)ei + NE + e);
            d0 = (int)dd.x;
            d1 = (int)dd.y;
        } else {
            uint2 dd = *(const uint2*)((const int*)ei + NE + e);
            d0 = (int)dd.x;
            d1 = (int)dd.y;
        }
        int r0 = atomicAdd(&hist[d0 >> 9], 1);
        int r1 = atomicAdd(&hist[d1 >> 9], 1);
        dr[2 * k] = ((unsigned)r0 << 18) | (unsigned)d0;
        dr[2 * k + 1] = ((unsigned)r1 << 18) | (unsigned)d1;
    }
    __syncthreads();

    // exclusive scan of 392 counts: pair-sum + 64-lane shfl scan + wave combine
    int h0 = 0, h1 = 0, p = 0;
    if (t < NBK / 2) {
        h0 = hist[2 * t];
        h1 = hist[2 * t + 1];
        p = h0 + h1;
    }
    int lane = t & 63;
    int w = t >> 6;
    int incl = p;
#pragma unroll
    for (int off = 1; off < 64; off <<= 1) {
        int v = __shfl_up(incl, off, 64);
        if (lane >= off) incl += v;
    }
    if (lane == 63) wsum[w] = incl;
    __syncthreads();
    int wbase = 0;
#pragma unroll
    for (int ww = 0; ww < 4; ++ww) wbase += (ww < w) ? wsum[ww] : 0;
    int ex = wbase + incl - p;
    if (t < NBK / 2) {
        lofs[2 * t] = ex;
        lofs[2 * t + 1] = ex + h0;
    }
    if (t < NBK) gofs[t] = atomicAdd(&gcur[(segbase + t) * GSTR], hist[t]);
    if (t + 256 < NBK)
        gofs[t + 256] = atomicAdd(&gcur[(segbase + t + 256) * GSTR], hist[t + 256]);
    __syncthreads();

    // stage at lofs[bucket] + rank (no second atomic); src pairs (16B loads)
#pragma unroll
    for (int k = 0; k < IPT2; ++k) {
        int e = tile0 + k * 512 + 2 * t;
        int s0, s1;
        if (fl) {
            ulonglong2 ss = *(const ulonglong2*)((const long long*)ei + e);
            s0 = (int)ss.x;
            s1 = (int)ss.y;
        } else {
            uint2 ss = *(const uint2*)((const int*)ei + e);
            s0 = (int)ss.x;
            s1 = (int)ss.y;
        }
        unsigned v0 = dr[2 * k], v1 = dr[2 * k + 1];
        int d0 = (int)(v0 & 0x3FFFFu), d1 = (int)(v1 & 0x3FFFFu);
        int r0 = (int)(v0 >> 18), r1 = (int)(v1 >> 18);
        stage[lofs[d0 >> 9] + r0] = ((unsigned)(d0 & 511) << 18) | (unsigned)s0;
        stage[lofs[d1 >> 9] + r1] = ((unsigned)(d1 & 511) << 18) | (unsigned)s1;
    }
    __syncthreads();

    // coalesced write-out; bucket of slot i via binary search on lofs
    for (int i = t; i < TILE; i += 256) {
        int lo = 0, hi = NBK - 1;
#pragma unroll
        for (int it = 0; it < 9; ++it) {
            int mid = (lo + hi + 1) >> 1;
            if (lofs[mid] <= i) lo = mid;
            else hi = mid - 1;
        }
        int b = lo;
        unsigned pack = stage[i];
        int seg = segbase + b;
        int dest = gofs[b] + (i - lofs[b]);
        if (dest < (seg + 1) * SCAP) {
            binned[dest] = pack;
        } else {  // overflow (never in practice)
            int op = atomicAdd(&gcur[NSEG * GSTR], 1);
            if (op < OVFCAP) {
                int d = (b << 9) | (int)(pack >> 18);
                int s = (int)(pack & 0x3FFFF);
                ovf[op] = ((ull)d << 32) | (unsigned)s;
            }
        }
    }
}

// bucket-local counting sort over 8 sub-segments, key = (dlow<<1)|(src>=PHB).
// count -> scan -> cursor-atomic scatter (cnt reused as cursor; order within a
// key is irrelevant downstream). Also computes dinv = rsqrt(degree+1).
__global__ __launch_bounds__(1024, 8) void k_sort(const int* __restrict__ gcur,
                                                  const unsigned* __restrict__ binned,
                                                  const ull* __restrict__ ovf,
                                                  unsigned* __restrict__ csr,
                                                  float* __restrict__ dinv,
                                                  int* __restrict__ rsg,
                                                  unsigned* __restrict__ spl) {
    __shared__ int cnt[1024];
    __shared__ int excl[1024];
    __shared__ int wsum[16];
    int b = blockIdx.x;
    int t = threadIdx.x;
    cnt[t] = 0;
    __syncthreads();
    int nov = min(gcur[NSEG * GSTR], OVFCAP);

    // pass 1: count keys across the 8 sub-segments (fire-and-forget atomics)
    for (int s = 0; s < NSUB; ++s) {
        int seg = s * NBK + b;
        int sb = seg * SCAP;
        int n = min(gcur[seg * GSTR] - sb, SCAP);
        for (int i = t; i < n; i += 1024) {
            unsigned pack = binned[sb + i];
            int key = ((int)(pack >> 18) << 1) | ((pack & 0x3FFFF) >= PHB ? 1 : 0);
            atomicAdd(&cnt[key], 1);
        }
    }
    __syncthreads();

    // exclusive scan of 1024 counts: 64-lane shfl scan + 16-wave combine
    int c = cnt[t];
    int lane = t & 63;
    int w = t >> 6;
    int incl = c;
#pragma unroll
    for (int off = 1; off < 64; off <<= 1) {
        int v = __shfl_up(incl, off, 64);
        if (lane >= off) incl += v;
    }
    if (lane == 63) wsum[w] = incl;
    __syncthreads();
    int wbase = 0;
#pragma unroll
    for (int ww = 0; ww < 16; ++ww) wbase += (ww < w) ? wsum[ww] : 0;
    excl[t] = wbase + incl - c;
    __syncthreads();

    if (t < 512) {
        int g = (b << 9) + t;
        if (g < NN) {
            int c0 = cnt[2 * t];
            int c1 = cnt[2 * t + 1];
            int extra = 0;
            for (int k = 0; k < nov; ++k) extra += ((int)(ovf[k] >> 32) == g);
            dinv[g] = rsqrtf((float)(c0 + c1 + extra) + 1.0f);
            rsg[g] = b * CCAP + excl[2 * t];                 // csr row start (absolute)
            spl[g] = (unsigned)c0 | ((unsigned)c1 << 16);    // phase sub-counts
        }
    }
    __syncthreads();  // dinv readers of cnt done before cursor overwrite

    cnt[t] = b * CCAP + excl[t];  // absolute csr cursor
    __syncthreads();

    // pass 2: scatter via cursor atomics
    for (int s = 0; s < NSUB; ++s) {
        int seg = s * NBK + b;
        int sb = seg * SCAP;
        int n = min(gcur[seg * GSTR] - sb, SCAP);
        for (int i = t; i < n; i += 1024) {
            unsigned pack = binned[sb + i];
            unsigned src = pack & 0x3FFFF;
            int key = ((int)(pack >> 18) << 1) | (src >= PHB ? 1 : 0);
            int pos = atomicAdd(&cnt[key], 1);
            csr[pos] = src;
        }
    }
}

// xph[s] = fp16(dinv[s]*x[s]) padded to 16 halves (one aligned 32B row).
__global__ void k_prep(const float* __restrict__ x, const float* __restrict__ dinv,
                       __half* __restrict__ xph) {
    int i = blockIdx.x * blockDim.x + threadIdx.x;
    if (i >= NN * 16) return;
    int node = i >> 4;
    int c = i & 15;
    float v = (c < IC) ? dinv[node] * x[node * IC + c] : 0.0f;
    xph[i] = __float2half(v);
}

// Layer-1 aggregation. Phase q = blockIdx&1 (XCD-parity affinity: each XCD L2
// holds one 3.2MB phase gather region). csr stream + partial store are
// non-temporal so they don't evict the gather region. 4 lanes per dst node.
__global__ __launch_bounds__(256) void k_agg1(const int* __restrict__ rsg,
                                              const unsigned* __restrict__ spl,
                                              const unsigned* __restrict__ csr,
                                              const __half* __restrict__ xph,
                                              float* __restrict__ partial) {
    int t = threadIdx.x;
    int q = blockIdx.x & 1;
    int blk = blockIdx.x >> 1;
    int g = t >> 2;
    int qq = t & 3;
    int i = blk * 64 + g;
    unsigned sp = spl[i];
    int n0 = (int)(sp & 0xFFFF);
    int n1 = (int)(sp >> 16);
    int beg = rsg[i] + (q ? n0 : 0);
    int end = beg + (q ? n1 : n0);

    float ax = 0.0f, ay = 0.0f, az = 0.0f, aw = 0.0f;
    int j = beg;
    for (; j + 1 < end; j += 2) {
        int s0 = (int)__builtin_nontemporal_load(csr + j);
        int s1 = (int)__builtin_nontemporal_load(csr + j + 1);
        uint2 u0 = *(const uint2*)(xph + (size_t)s0 * 16 + 4 * qq);
        uint2 u1 = *(const uint2*)(xph + (size_t)s1 * 16 + 4 * qq);
        float2 f0 = __half22float2(*(__half2*)&u0.x);
        float2 f1 = __half22float2(*(__half2*)&u0.y);
        float2 f2 = __half22float2(*(__half2*)&u1.x);
        float2 f3 = __half22float2(*(__half2*)&u1.y);
        ax += f0.x + f2.x;
        ay += f0.y + f2.y;
        az += f1.x + f3.x;
        aw += f1.y + f3.y;
    }
    if (j < end) {
        int s0 = (int)__builtin_nontemporal_load(csr + j);
        uint2 u0 = *(const uint2*)(xph + (size_t)s0 * 16 + 4 * qq);
        float2 f0 = __half22float2(*(__half2*)&u0.x);
        float2 f1 = __half22float2(*(__half2*)&u0.y);
        ax += f0.x;
        ay += f0.y;
        az += f1.x;
        aw += f1.y;
    }
    f4v r = {ax, ay, az, aw};
    __builtin_nontemporal_store(r, (f4v*)(partial + ((size_t)q * NN + i) * 16 + 4 * qq));
}

// Sum phase partials + self loop + overflow-list fixup, then the fused MLP.
// partial/xph reads are one-shot streams -> non-temporal.
__global__ __launch_bounds__(256) void k_mlp(const float* __restrict__ partial,
                                             const __half* __restrict__ xph,
                                             const int* __restrict__ gcur,
                                             const ull* __restrict__ ovf,
                                             const float* __restrict__ dinv,
                                             const float* __restrict__ W1,
                                             const float* __restrict__ b1,
                                             const float* __restrict__ W2,
                                             const float* __restrict__ b2,
                                             float2* __restrict__ h2bp,
                                             float2* __restrict__ selfout) {
    __shared__ float sW1[IC * HC];
    __shared__ float sb1[HC];
    __shared__ float sW2[HC * OC];
    __shared__ float sb2[OC];
    int t = threadIdx.x;
    if (t < IC * HC) sW1[t] = W1[t];
    if (t < HC) sb1[t] = b1[t];
    if (t < HC * OC) sW2[t] = W2[t];
    if (t < OC) sb2[t] = b2[t];
    __syncthreads();

    int i = blockIdx.x * 256 + t;
    if (i >= NN) return;

    float dv = dinv[i];
    const f4v* p0 = (const f4v*)(partial + (size_t)i * 16);
    const f4v* p1 = (const f4v*)(partial + ((size_t)NN + i) * 16);
    const ull* sp = (const ull*)(xph + (size_t)i * 16);

    float agg[16];
#pragma unroll
    for (int c4 = 0; c4 < 4; ++c4) {
        f4v a = __builtin_nontemporal_load(p0 + c4);
        f4v b = __builtin_nontemporal_load(p1 + c4);
        ull u = __builtin_nontemporal_load(sp + c4);
        unsigned ux = (unsigned)(u & 0xFFFFFFFFu);
        unsigned uy = (unsigned)(u >> 32);
        float2 s0 = __half22float2(*(__half2*)&ux);
        float2 s1 = __half22float2(*(__half2*)&uy);
        agg[4 * c4 + 0] = a.x + b.x + s0.x;
        agg[4 * c4 + 1] = a.y + b.y + s0.y;
        agg[4 * c4 + 2] = a.z + b.z + s1.x;
        agg[4 * c4 + 3] = a.w + b.w + s1.y;
    }

    // overflow fixup (nov==0 in practice)
    int nov = min(gcur[NSEG * GSTR], OVFCAP);
    for (int k = 0; k < nov; ++k) {
        ull e = ovf[k];
        if ((int)(e >> 32) == i) {
            int s = (int)(e & 0xFFFFFFFFu);
            for (int c = 0; c < IC; ++c)
                agg[c] += __half2float(xph[(size_t)s * 16 + c]);
        }
    }

    float tt[IC];
#pragma unroll
    for (int c = 0; c < IC; ++c) tt[c] = dv * agg[c];

    float r[HC];
#pragma unroll
    for (int f = 0; f < HC; ++f) {
        float a = sb1[f];
#pragma unroll
        for (int c = 0; c < IC; ++c) a = fmaf(tt[c], sW1[c * HC + f], a);
        r[f] = fmaxf(a, 0.0f);
    }

    float o0 = 0.0f, o1 = 0.0f;
#pragma unroll
    for (int f = 0; f < HC; ++f) {
        o0 = fmaf(r[f], sW2[f * OC + 0], o0);
        o1 = fmaf(r[f], sW2[f * OC + 1], o1);
    }
    h2bp[i] = make_float2(o0 * dv, o1 * dv);  // dinv-prescaled for layer 2
    selfout[i] = make_float2(o0 * dv * dv + sb2[0], o1 * dv * dv + sb2[1]);
}

// layer-2: out[i] = selfout[i] + dinv[i] * (sum h2bp[src] + ovf matches).
// 2 lanes per node (split edge range), shfl_xor combine. csr stream is
// non-temporal; the 1.6MB h2bp gather region stays cached.
__global__ __launch_bounds__(256) void k_agg2(const int* __restrict__ rsg,
                                              const unsigned* __restrict__ spl,
                                              const unsigned* __restrict__ csr,
                                              const int* __restrict__ gcur,
                                              const ull* __restrict__ ovf,
                                              const float* __restrict__ dinv,
                                              const float2* __restrict__ h2bp,
                                              const float2* __restrict__ selfout,
                                              float2* __restrict__ out) {
    int tt = blockIdx.x * 256 + threadIdx.x;
    int i = tt >> 1;
    int h = tt & 1;
    if (i >= NN) return;
    unsigned sp = spl[i];
    int beg = rsg[i];
    int end = beg + (int)(sp & 0xFFFF) + (int)(sp >> 16);
    float ax = 0.0f, ay = 0.0f;
    int j = beg + h;
    for (; j + 2 < end; j += 4) {
        int s0 = (int)__builtin_nontemporal_load(csr + j);
        int s1 = (int)__builtin_nontemporal_load(csr + j + 2);
        float2 h0 = h2bp[s0];
        float2 h1 = h2bp[s1];
        ax += h0.x + h1.x;
        ay += h0.y + h1.y;
    }
    if (j < end) {
        int s0 = (int)__builtin_nontemporal_load(csr + j);
        float2 h0 = h2bp[s0];
        ax += h0.x;
        ay += h0.y;
    }
    ax += __shfl_xor(ax, 1);
    ay += __shfl_xor(ay, 1);
    if (h == 0) {
        // overflow fixup (nov==0 in practice); h2bp already dinv[src]-prescaled
        int nov = min(gcur[NSEG * GSTR], OVFCAP);
        for (int k = 0; k < nov; ++k) {
            ull e = ovf[k];
            if ((int)(e >> 32) == i) {
                float2 hh = h2bp[(int)(e & 0xFFFFFFFFu)];
                ax += hh.x;
                ay += hh.y;
            }
        }
        float dv = dinv[i];
        float2 so = selfout[i];
        out[i] = make_float2(so.x + dv * ax, so.y + dv * ay);
    }
}

extern "C" void kernel_launch(void* const* d_in, const int* in_sizes, int n_in,
                              void* d_out, int out_size, void* d_ws, size_t ws_size,
                              hipStream_t stream) {
    const float* x = (const float*)d_in[0];
    const void* ei = d_in[1];
    // d_in[2] = edge_attr (unused)
    const float* W1 = (const float*)d_in[3];
    const float* b1 = (const float*)d_in[4];
    const float* W2 = (const float*)d_in[5];
    const float* b2 = (const float*)d_in[6];
    float* out = (float*)d_out;

    ull* ovf = (ull*)d_ws;                              // OVFCAP       (0.5MB)
    int* gcur = (int*)(ovf + OVFCAP);                   // (NSEG+1)*16 ints (200KB)
    int* flag = gcur + (NSEG + 1) * GSTR;               // 4
    int* rsg = flag + 4;                                // NN
    unsigned* spl = (unsigned*)(rsg + NN);              // NN
    float* dinv = (float*)(spl + NN);                   // NN
    __half* xph = (__half*)(dinv + NN);                 // NN*16 halves (6.4MB)
    float2* h2bp = (float2*)(xph + (size_t)NN * 16);    // NN
    float2* selfout = h2bp + NN;                        // NN
    unsigned* binned = (unsigned*)(selfout + NN);       // NSEG*SCAP    (35.3MB)
    float* partial = (float*)binned;                    // 2*NN*16 f32 (25.6MB), overlays
                                                        // binned (dead after k_sort)
    unsigned* csr = binned + (size_t)NSEG * SCAP;       // NBK*CCAP     (35.3MB)

    k_init<<<(NSEG + 1 + 255) / 256, 256, 0, stream>>>(gcur, ei, flag);
    k_binA<<<NTILE, 256, 0, stream>>>(ei, flag, gcur, binned, ovf);
    k_sort<<<NBK, 1024, 0, stream>>>(gcur, binned, ovf, csr, dinv, rsg, spl);
    k_prep<<<(NN * 16 + 255) / 256, 256, 0, stream>>>(x, dinv, xph);
    k_agg1<<<2 * NAGG, 256, 0, stream>>>(rsg, spl, csr, xph, partial);
    k_mlp<<<NB, 256, 0, stream>>>(partial, xph, gcur, ovf, dinv, W1, b1, W2, b2,
                                  h2bp, selfout);
    k_agg2<<<(NN * 2 + 255) / 256, 256, 0, stream>>>(rsg, spl, csr, gcur, ovf, dinv,
                                                     h2bp, selfout, (float2*)out);
}

// Round 3
// 365.844 us; speedup vs baseline: 1.1147x; 1.1147x over previous
//
#include <hip/hip_runtime.h>
#include <hip/hip_fp16.h>

// GCN 2-layer: N=200000, E=6400000, 14 -> 16(relu) -> 2.
// Round 15: 4 source-phases for the layer-1 gather. Round-14 post-mortem:
// nt loads on csr bypassed L1 (4x duplicate + within-line reuse lost) ->
// regression; and the 3.2MB phase region + streams sits just past the L2
// LRU cliff (85% miss). Fix is capacity, not hints:
//   - sort key = (dlow<<2)|phase(src/50000): 4 phases, spl = 4x8-bit counts.
//   - agg1 split into TWO kernels over ONE partial[2] buffer (no ws growth):
//     A: phases {0,1} plain-store; B: phases {2,3} read-modify-write.
//     q = bid&1 in each -> XCD parity affinity: each XCD's gather region is
//     1.6MB (well under the cliff). nt only on partial stores + B's
//     zero-reuse partial stream read; csr/xph loads are normal (L1-served).
// Pipeline: init -> binA -> sort(+dinv) -> prep -> agg1A -> agg1B -> mlp -> agg2.

constexpr int NN = 200000;
constexpr int NE = 6400000;
constexpr int IC = 14;
constexpr int HC = 16;
constexpr int OC = 2;

constexpr int NBK = 392;                   // buckets of 512 dst nodes
constexpr int NSUB = 8;                    // sub-segments per bucket (bid&7)
constexpr int SCAP = 2816;                 // per (sub,bucket) cap: mean 2058 + 16.7 sigma
constexpr int NSEG = NSUB * NBK;           // 3136 segments
constexpr int CCAP = NSUB * SCAP;          // 22528 csr per-bucket capacity
constexpr int TILE = 5120;                 // edges per binA tile
constexpr int IPT = TILE / 256;            // 20
constexpr int IPT2 = IPT / 2;              // 10 pair-loads per thread
constexpr int NTILE = NE / TILE;           // 1250
constexpr int OVFCAP = 65536;
constexpr int NB = (NN + 255) / 256;       // 782
constexpr int NAGG = NN / 64;              // 3125 blocks per phase-pair half
constexpr int GSTR = 16;                   // gcur stride: 1 counter per 64B line

typedef unsigned long long ull;
typedef float f4v __attribute__((ext_vector_type(4)));

__device__ __forceinline__ int phase_of(unsigned src) {
    return src >= 100000u ? (src >= 150000u ? 3 : 2) : (src >= 50000u ? 1 : 0);
}

// init gcur (padded) + ovf counter + dtype flag
__global__ void k_init(int* __restrict__ gcur, const void* __restrict__ ei,
                       int* __restrict__ flag) {
    int i = blockIdx.x * blockDim.x + threadIdx.x;
    if (i < NSEG) gcur[i * GSTR] = i * SCAP;
    else if (i == NSEG) gcur[i * GSTR] = 0;  // overflow counter
    if (i == 500) {  // one thread sniffs edge dtype
        const ull* p = (const ull*)ei;
        ull acc = 0ULL;
        for (int k = 0; k < 64; ++k) acc |= (p[k] >> 32);
        *flag = (acc == 0ULL) ? 1 : 0;  // 1 => int64 indices, 0 => int32
    }
}

// Bin edges by dst>>9 into per-(sub,bucket) global segments, sub = bid&7.
// Rank captured from the histogram atomic; LDS-staged for coalesced segment
// write-out. Bucket of a stage slot recovered by binary search over lofs.
__global__ __launch_bounds__(256, 6) void k_binA(const void* __restrict__ ei,
                                                 const int* __restrict__ flag,
                                                 int* __restrict__ gcur,
                                                 unsigned* __restrict__ binned,
                                                 ull* __restrict__ ovf) {
    __shared__ int hist[NBK];
    __shared__ int lofs[NBK];
    __shared__ int gofs[NBK];
    __shared__ int wsum[4];
    __shared__ unsigned stage[TILE];

    int t = threadIdx.x;
    int fl = *flag;
    int tile0 = blockIdx.x * TILE;
    int segbase = (blockIdx.x & (NSUB - 1)) * NBK;

    if (t < NBK) hist[t] = 0;
    if (t + 256 < NBK) hist[t + 256] = 0;
    __syncthreads();

    // pass 1: dst pairs (16B loads) + rank capture (dr = rank<<18 | dst)
    unsigned dr[IPT];
#pragma unroll
    for (int k = 0; k < IPT2; ++k) {
        int e = tile0 + k * 512 + 2 * t;
        int d0, d1;
        if (fl) {
            ulonglong2 dd = *(const ulonglong2*)((const long long*)ei + NE + e);
            d0 = (int)dd.x;
            d1 = (int)dd.y;
        } else {
            uint2 dd = *(const uint2*)((const int*)ei + NE + e);
            d0 = (int)dd.x;
            d1 = (int)dd.y;
        }
        int r0 = atomicAdd(&hist[d0 >> 9], 1);
        int r1 = atomicAdd(&hist[d1 >> 9], 1);
        dr[2 * k] = ((unsigned)r0 << 18) | (unsigned)d0;
        dr[2 * k + 1] = ((unsigned)r1 << 18) | (unsigned)d1;
    }
    __syncthreads();

    // exclusive scan of 392 counts: pair-sum + 64-lane shfl scan + wave combine
    int h0 = 0, h1 = 0, p = 0;
    if (t < NBK / 2) {
        h0 = hist[2 * t];
        h1 = hist[2 * t + 1];
        p = h0 + h1;
    }
    int lane = t & 63;
    int w = t >> 6;
    int incl = p;
#pragma unroll
    for (int off = 1; off < 64; off <<= 1) {
        int v = __shfl_up(incl, off, 64);
        if (lane >= off) incl += v;
    }
    if (lane == 63) wsum[w] = incl;
    __syncthreads();
    int wbase = 0;
#pragma unroll
    for (int ww = 0; ww < 4; ++ww) wbase += (ww < w) ? wsum[ww] : 0;
    int ex = wbase + incl - p;
    if (t < NBK / 2) {
        lofs[2 * t] = ex;
        lofs[2 * t + 1] = ex + h0;
    }
    if (t < NBK) gofs[t] = atomicAdd(&gcur[(segbase + t) * GSTR], hist[t]);
    if (t + 256 < NBK)
        gofs[t + 256] = atomicAdd(&gcur[(segbase + t + 256) * GSTR], hist[t + 256]);
    __syncthreads();

    // stage at lofs[bucket] + rank (no second atomic); src pairs (16B loads)
#pragma unroll
    for (int k = 0; k < IPT2; ++k) {
        int e = tile0 + k * 512 + 2 * t;
        int s0, s1;
        if (fl) {
            ulonglong2 ss = *(const ulonglong2*)((const long long*)ei + e);
            s0 = (int)ss.x;
            s1 = (int)ss.y;
        } else {
            uint2 ss = *(const uint2*)((const int*)ei + e);
            s0 = (int)ss.x;
            s1 = (int)ss.y;
        }
        unsigned v0 = dr[2 * k], v1 = dr[2 * k + 1];
        int d0 = (int)(v0 & 0x3FFFFu), d1 = (int)(v1 & 0x3FFFFu);
        int r0 = (int)(v0 >> 18), r1 = (int)(v1 >> 18);
        stage[lofs[d0 >> 9] + r0] = ((unsigned)(d0 & 511) << 18) | (unsigned)s0;
        stage[lofs[d1 >> 9] + r1] = ((unsigned)(d1 & 511) << 18) | (unsigned)s1;
    }
    __syncthreads();

    // coalesced write-out; bucket of slot i via binary search on lofs
    for (int i = t; i < TILE; i += 256) {
        int lo = 0, hi = NBK - 1;
#pragma unroll
        for (int it = 0; it < 9; ++it) {
            int mid = (lo + hi + 1) >> 1;
            if (lofs[mid] <= i) lo = mid;
            else hi = mid - 1;
        }
        int b = lo;
        unsigned pack = stage[i];
        int seg = segbase + b;
        int dest = gofs[b] + (i - lofs[b]);
        if (dest < (seg + 1) * SCAP) {
            binned[dest] = pack;
        } else {  // overflow (never in practice)
            int op = atomicAdd(&gcur[NSEG * GSTR], 1);
            if (op < OVFCAP) {
                int d = (b << 9) | (int)(pack >> 18);
                int s = (int)(pack & 0x3FFFF);
                ovf[op] = ((ull)d << 32) | (unsigned)s;
            }
        }
    }
}

// bucket-local counting sort over 8 sub-segments, key = (dlow<<2)|phase(src).
// count -> scan(2048) -> cursor-atomic scatter (cnt reused as cursor).
// Also computes dinv = rsqrt(degree+1) and packs 4x8-bit phase counts.
__global__ __launch_bounds__(1024, 8) void k_sort(const int* __restrict__ gcur,
                                                  const unsigned* __restrict__ binned,
                                                  const ull* __restrict__ ovf,
                                                  unsigned* __restrict__ csr,
                                                  float* __restrict__ dinv,
                                                  int* __restrict__ rsg,
                                                  unsigned* __restrict__ spl) {
    __shared__ int cnt[2048];
    __shared__ int excl[2048];
    __shared__ int wsum[16];
    int b = blockIdx.x;
    int t = threadIdx.x;
    cnt[t] = 0;
    cnt[t + 1024] = 0;
    __syncthreads();
    int nov = min(gcur[NSEG * GSTR], OVFCAP);

    // pass 1: count keys across the 8 sub-segments (fire-and-forget atomics)
    for (int s = 0; s < NSUB; ++s) {
        int seg = s * NBK + b;
        int sb = seg * SCAP;
        int n = min(gcur[seg * GSTR] - sb, SCAP);
        for (int i = t; i < n; i += 1024) {
            unsigned pack = binned[sb + i];
            unsigned src = pack & 0x3FFFFu;
            int key = ((int)(pack >> 18) << 2) | phase_of(src);
            atomicAdd(&cnt[key], 1);
        }
    }
    __syncthreads();

    // exclusive scan of 2048 counts: pair-sum + 1024-lane scan (16 waves)
    int h0 = cnt[2 * t];
    int h1 = cnt[2 * t + 1];
    int p = h0 + h1;
    int lane = t & 63;
    int w = t >> 6;
    int incl = p;
#pragma unroll
    for (int off = 1; off < 64; off <<= 1) {
        int v = __shfl_up(incl, off, 64);
        if (lane >= off) incl += v;
    }
    if (lane == 63) wsum[w] = incl;
    __syncthreads();
    int wbase = 0;
#pragma unroll
    for (int ww = 0; ww < 16; ++ww) wbase += (ww < w) ? wsum[ww] : 0;
    int ex = wbase + incl - p;
    excl[2 * t] = ex;
    excl[2 * t + 1] = ex + h0;
    __syncthreads();

    if (t < 512) {
        int g = (b << 9) + t;
        if (g < NN) {
            int c0 = cnt[4 * t];
            int c1 = cnt[4 * t + 1];
            int c2 = cnt[4 * t + 2];
            int c3 = cnt[4 * t + 3];
            int extra = 0;
            for (int k = 0; k < nov; ++k) extra += ((int)(ovf[k] >> 32) == g);
            dinv[g] = rsqrtf((float)(c0 + c1 + c2 + c3 + extra) + 1.0f);
            rsg[g] = b * CCAP + excl[4 * t];                 // csr row start (absolute)
            spl[g] = (unsigned)c0 | ((unsigned)c1 << 8) |
                     ((unsigned)c2 << 16) | ((unsigned)c3 << 24);
        }
    }
    __syncthreads();  // stats readers of cnt done before cursor overwrite

    cnt[t] = b * CCAP + excl[t];            // absolute csr cursors
    cnt[t + 1024] = b * CCAP + excl[t + 1024];
    __syncthreads();

    // pass 2: scatter via cursor atomics
    for (int s = 0; s < NSUB; ++s) {
        int seg = s * NBK + b;
        int sb = seg * SCAP;
        int n = min(gcur[seg * GSTR] - sb, SCAP);
        for (int i = t; i < n; i += 1024) {
            unsigned pack = binned[sb + i];
            unsigned src = pack & 0x3FFFFu;
            int key = ((int)(pack >> 18) << 2) | phase_of(src);
            int pos = atomicAdd(&cnt[key], 1);
            csr[pos] = src;
        }
    }
}

// xph[s] = fp16(dinv[s]*x[s]) padded to 16 halves (one aligned 32B row).
__global__ void k_prep(const float* __restrict__ x, const float* __restrict__ dinv,
                       __half* __restrict__ xph) {
    int i = blockIdx.x * blockDim.x + threadIdx.x;
    if (i >= NN * 16) return;
    int node = i >> 4;
    int c = i & 15;
    float v = (c < IC) ? dinv[node] * x[node * IC + c] : 0.0f;
    xph[i] = __float2half(v);
}

// Layer-1 aggregation, phases pbase..pbase+1. q2 = bid&1 -> XCD parity
// affinity: each XCD gathers from ONE 1.6MB phase region. partial buffer
// index = q2 (buffer 0 accumulates phases 0+2, buffer 1 phases 1+3).
// acc=1 (second pass) read-modify-writes. 4 lanes per dst node.
__global__ __launch_bounds__(256) void k_agg1(const int* __restrict__ rsg,
                                              const unsigned* __restrict__ spl,
                                              const unsigned* __restrict__ csr,
                                              const __half* __restrict__ xph,
                                              float* __restrict__ partial,
                                              int pbase, int acc) {
    int t = threadIdx.x;
    int q2 = blockIdx.x & 1;
    int ph = pbase + q2;
    int blk = blockIdx.x >> 1;
    int g = t >> 2;
    int qq = t & 3;
    int i = blk * 64 + g;
    unsigned sp = spl[i];
    int c0 = (int)(sp & 255u);
    int c1 = (int)((sp >> 8) & 255u);
    int c2 = (int)((sp >> 16) & 255u);
    int c3 = (int)(sp >> 24);
    int off = (ph > 0 ? c0 : 0) + (ph > 1 ? c1 : 0) + (ph > 2 ? c2 : 0);
    int len = ph == 0 ? c0 : ph == 1 ? c1 : ph == 2 ? c2 : c3;
    int beg = rsg[i] + off;
    int end = beg + len;

    float ax = 0.0f, ay = 0.0f, az = 0.0f, aw = 0.0f;
    int j = beg;
    for (; j + 1 < end; j += 2) {
        int s0 = csr[j];
        int s1 = csr[j + 1];
        uint2 u0 = *(const uint2*)(xph + (size_t)s0 * 16 + 4 * qq);
        uint2 u1 = *(const uint2*)(xph + (size_t)s1 * 16 + 4 * qq);
        float2 f0 = __half22float2(*(__half2*)&u0.x);
        float2 f1 = __half22float2(*(__half2*)&u0.y);
        float2 f2 = __half22float2(*(__half2*)&u1.x);
        float2 f3 = __half22float2(*(__half2*)&u1.y);
        ax += f0.x + f2.x;
        ay += f0.y + f2.y;
        az += f1.x + f3.x;
        aw += f1.y + f3.y;
    }
    if (j < end) {
        int s0 = csr[j];
        uint2 u0 = *(const uint2*)(xph + (size_t)s0 * 16 + 4 * qq);
        float2 f0 = __half22float2(*(__half2*)&u0.x);
        float2 f1 = __half22float2(*(__half2*)&u0.y);
        ax += f0.x;
        ay += f0.y;
        az += f1.x;
        aw += f1.y;
    }
    f4v r = {ax, ay, az, aw};
    float* dst = partial + ((size_t)q2 * NN + i) * 16 + 4 * qq;
    if (acc) {
        f4v o = __builtin_nontemporal_load((const f4v*)dst);  // zero-reuse stream
        r += o;
    }
    __builtin_nontemporal_store(r, (f4v*)dst);
}

// Sum phase partials + self loop + overflow-list fixup, then the fused MLP.
__global__ __launch_bounds__(256) void k_mlp(const float* __restrict__ partial,
                                             const __half* __restrict__ xph,
                                             const int* __restrict__ gcur,
                                             const ull* __restrict__ ovf,
                                             const float* __restrict__ dinv,
                                             const float* __restrict__ W1,
                                             const float* __restrict__ b1,
                                             const float* __restrict__ W2,
                                             const float* __restrict__ b2,
                                             float2* __restrict__ h2bp,
                                             float2* __restrict__ selfout) {
    __shared__ float sW1[IC * HC];
    __shared__ float sb1[HC];
    __shared__ float sW2[HC * OC];
    __shared__ float sb2[OC];
    int t = threadIdx.x;
    if (t < IC * HC) sW1[t] = W1[t];
    if (t < HC) sb1[t] = b1[t];
    if (t < HC * OC) sW2[t] = W2[t];
    if (t < OC) sb2[t] = b2[t];
    __syncthreads();

    int i = blockIdx.x * 256 + t;
    if (i >= NN) return;

    float dv = dinv[i];
    const float4* p0 = (const float4*)(partial + (size_t)i * 16);
    const float4* p1 = (const float4*)(partial + ((size_t)NN + i) * 16);
    const uint2* sp = (const uint2*)(xph + (size_t)i * 16);

    float agg[16];
#pragma unroll
    for (int c4 = 0; c4 < 4; ++c4) {
        float4 a = p0[c4];
        float4 b = p1[c4];
        uint2 u = sp[c4];
        float2 s0 = __half22float2(*(__half2*)&u.x);
        float2 s1 = __half22float2(*(__half2*)&u.y);
        agg[4 * c4 + 0] = a.x + b.x + s0.x;
        agg[4 * c4 + 1] = a.y + b.y + s0.y;
        agg[4 * c4 + 2] = a.z + b.z + s1.x;
        agg[4 * c4 + 3] = a.w + b.w + s1.y;
    }

    // overflow fixup (nov==0 in practice)
    int nov = min(gcur[NSEG * GSTR], OVFCAP);
    for (int k = 0; k < nov; ++k) {
        ull e = ovf[k];
        if ((int)(e >> 32) == i) {
            int s = (int)(e & 0xFFFFFFFFu);
            for (int c = 0; c < IC; ++c)
                agg[c] += __half2float(xph[(size_t)s * 16 + c]);
        }
    }

    float tt[IC];
#pragma unroll
    for (int c = 0; c < IC; ++c) tt[c] = dv * agg[c];

    float r[HC];
#pragma unroll
    for (int f = 0; f < HC; ++f) {
        float a = sb1[f];
#pragma unroll
        for (int c = 0; c < IC; ++c) a = fmaf(tt[c], sW1[c * HC + f], a);
        r[f] = fmaxf(a, 0.0f);
    }

    float o0 = 0.0f, o1 = 0.0f;
#pragma unroll
    for (int f = 0; f < HC; ++f) {
        o0 = fmaf(r[f], sW2[f * OC + 0], o0);
        o1 = fmaf(r[f], sW2[f * OC + 1], o1);
    }
    h2bp[i] = make_float2(o0 * dv, o1 * dv);  // dinv-prescaled for layer 2
    selfout[i] = make_float2(o0 * dv * dv + sb2[0], o1 * dv * dv + sb2[1]);
}

// layer-2: out[i] = selfout[i] + dinv[i] * (sum h2bp[src] + ovf matches).
// 2 lanes per node (split edge range), shfl_xor combine.
__global__ __launch_bounds__(256) void k_agg2(const int* __restrict__ rsg,
                                              const unsigned* __restrict__ spl,
                                              const unsigned* __restrict__ csr,
                                              const int* __restrict__ gcur,
                                              const ull* __restrict__ ovf,
                                              const float* __restrict__ dinv,
                                              const float2* __restrict__ h2bp,
                                              const float2* __restrict__ selfout,
                                              float2* __restrict__ out) {
    int tt = blockIdx.x * 256 + threadIdx.x;
    int i = tt >> 1;
    int h = tt & 1;
    if (i >= NN) return;
    unsigned sp = spl[i];
    int tot = (int)(sp & 255u) + (int)((sp >> 8) & 255u) +
              (int)((sp >> 16) & 255u) + (int)(sp >> 24);
    int beg = rsg[i];
    int end = beg + tot;
    float ax = 0.0f, ay = 0.0f;
    int j = beg + h;
    for (; j + 2 < end; j += 4) {
        float2 h0 = h2bp[csr[j]];
        float2 h1 = h2bp[csr[j + 2]];
        ax += h0.x + h1.x;
        ay += h0.y + h1.y;
    }
    if (j < end) {
        float2 h0 = h2bp[csr[j]];
        ax += h0.x;
        ay += h0.y;
    }
    ax += __shfl_xor(ax, 1);
    ay += __shfl_xor(ay, 1);
    if (h == 0) {
        // overflow fixup (nov==0 in practice); h2bp already dinv[src]-prescaled
        int nov = min(gcur[NSEG * GSTR], OVFCAP);
        for (int k = 0; k < nov; ++k) {
            ull e = ovf[k];
            if ((int)(e >> 32) == i) {
                float2 hh = h2bp[(int)(e & 0xFFFFFFFFu)];
                ax += hh.x;
                ay += hh.y;
            }
        }
        float dv = dinv[i];
        float2 so = selfout[i];
        out[i] = make_float2(so.x + dv * ax, so.y + dv * ay);
    }
}

extern "C" void kernel_launch(void* const* d_in, const int* in_sizes, int n_in,
                              void* d_out, int out_size, void* d_ws, size_t ws_size,
                              hipStream_t stream) {
    const float* x = (const float*)d_in[0];
    const void* ei = d_in[1];
    // d_in[2] = edge_attr (unused)
    const float* W1 = (const float*)d_in[3];
    const float* b1 = (const float*)d_in[4];
    const float* W2 = (const float*)d_in[5];
    const float* b2 = (const float*)d_in[6];
    float* out = (float*)d_out;

    ull* ovf = (ull*)d_ws;                              // OVFCAP       (0.5MB)
    int* gcur = (int*)(ovf + OVFCAP);                   // (NSEG+1)*16 ints (200KB)
    int* flag = gcur + (NSEG + 1) * GSTR;               // 4
    int* rsg = flag + 4;                                // NN
    unsigned* spl = (unsigned*)(rsg + NN);              // NN
    float* dinv = (float*)(spl + NN);                   // NN
    __half* xph = (__half*)(dinv + NN);                 // NN*16 halves (6.4MB)
    float2* h2bp = (float2*)(xph + (size_t)NN * 16);    // NN
    float2* selfout = h2bp + NN;                        // NN
    unsigned* binned = (unsigned*)(selfout + NN);       // NSEG*SCAP    (35.3MB)
    float* partial = (float*)binned;                    // 2*NN*16 f32 (25.6MB), overlays
                                                        // binned (dead after k_sort)
    unsigned* csr = binned + (size_t)NSEG * SCAP;       // NBK*CCAP     (35.3MB)

    k_init<<<(NSEG + 1 + 255) / 256, 256, 0, stream>>>(gcur, ei, flag);
    k_binA<<<NTILE, 256, 0, stream>>>(ei, flag, gcur, binned, ovf);
    k_sort<<<NBK, 1024, 0, stream>>>(gcur, binned, ovf, csr, dinv, rsg, spl);
    k_prep<<<(NN * 16 + 255) / 256, 256, 0, stream>>>(x, dinv, xph);
    k_agg1<<<2 * NAGG, 256, 0, stream>>>(rsg, spl, csr, xph, partial, 0, 0);
    k_agg1<<<2 * NAGG, 256, 0, stream>>>(rsg, spl, csr, xph, partial, 2, 1);
    k_mlp<<<NB, 256, 0, stream>>>(partial, xph, gcur, ovf, dinv, W1, b1, W2, b2,
                                  h2bp, selfout);
    k_agg2<<<(NN * 2 + 255) / 256, 256, 0, stream>>>(rsg, spl, csr, gcur, ovf, dinv,
                                                     h2bp, selfout, (float2*)out);
}

// Round 4
// 350.849 us; speedup vs baseline: 1.1624x; 1.0427x over previous
//
#include <hip/hip_runtime.h>
#include <hip/hip_fp16.h>

// GCN 2-layer: N=200000, E=6400000, 14 -> 16(relu) -> 2.
// Round 16: k_binA single-pass + occupancy push. binA was latency-bound
// (15% HBM, 20% VALU, 44% occ): TWO L3-latency passes over the edge arrays
// separated by barriers, 24 waves/CU.
//   - src now loaded in pass 1 and held in regs (pk=dlow|src, ra=rank|bucket;
//     20 held u32 = same count as the old dr[20]) -> pass 2 global loads gone.
//   - 512 threads/block (TILE unchanged): LDS ~24.6KB, 4 blocks x 8 waves =
//     32 waves/CU (was 24). __launch_bounds__(512,8) caps VGPR at 64.
//   - write-out bucket search seeded proportionally (b=(i*313)>>12, walk +-2)
//     ~3 LDS probes instead of 9.
// Pipeline: init -> binA -> sort(+dinv) -> prep -> agg1A -> agg1B -> mlp -> agg2.

constexpr int NN = 200000;
constexpr int NE = 6400000;
constexpr int IC = 14;
constexpr int HC = 16;
constexpr int OC = 2;

constexpr int NBK = 392;                   // buckets of 512 dst nodes
constexpr int NSUB = 8;                    // sub-segments per bucket (bid&7)
constexpr int SCAP = 2816;                 // per (sub,bucket) cap: mean 2058 + 16.7 sigma
constexpr int NSEG = NSUB * NBK;           // 3136 segments
constexpr int CCAP = NSUB * SCAP;          // 22528 csr per-bucket capacity
constexpr int TILE = 5120;                 // edges per binA tile
constexpr int BTH = 512;                   // binA threads
constexpr int IPT = TILE / BTH;            // 10
constexpr int IPT2 = IPT / 2;              // 5 pair-loads per thread
constexpr int NTILE = NE / TILE;           // 1250
constexpr int OVFCAP = 65536;
constexpr int NB = (NN + 255) / 256;       // 782
constexpr int NAGG = NN / 64;              // 3125 blocks per phase-pair half
constexpr int GSTR = 16;                   // gcur stride: 1 counter per 64B line

typedef unsigned long long ull;
typedef float f4v __attribute__((ext_vector_type(4)));

__device__ __forceinline__ int phase_of(unsigned src) {
    return src >= 100000u ? (src >= 150000u ? 3 : 2) : (src >= 50000u ? 1 : 0);
}

// init gcur (padded) + ovf counter + dtype flag
__global__ void k_init(int* __restrict__ gcur, const void* __restrict__ ei,
                       int* __restrict__ flag) {
    int i = blockIdx.x * blockDim.x + threadIdx.x;
    if (i < NSEG) gcur[i * GSTR] = i * SCAP;
    else if (i == NSEG) gcur[i * GSTR] = 0;  // overflow counter
    if (i == 500) {  // one thread sniffs edge dtype
        const ull* p = (const ull*)ei;
        ull acc = 0ULL;
        for (int k = 0; k < 64; ++k) acc |= (p[k] >> 32);
        *flag = (acc == 0ULL) ? 1 : 0;  // 1 => int64 indices, 0 => int32
    }
}

// Bin edges by dst>>9 into per-(sub,bucket) global segments, sub = bid&7.
// Single pass over edges: dst+src pair-loaded, rank captured from the
// histogram atomic, both held in regs across the scan. LDS-staged for
// coalesced segment write-out.
__global__ __launch_bounds__(BTH, 8) void k_binA(const void* __restrict__ ei,
                                                 const int* __restrict__ flag,
                                                 int* __restrict__ gcur,
                                                 unsigned* __restrict__ binned,
                                                 ull* __restrict__ ovf) {
    __shared__ int hist[NBK];
    __shared__ int lofs[NBK];
    __shared__ int gofs[NBK];
    __shared__ int wsum[BTH / 64];
    __shared__ unsigned stage[TILE];

    int t = threadIdx.x;
    int fl = *flag;
    int tile0 = blockIdx.x * TILE;
    int segbase = (blockIdx.x & (NSUB - 1)) * NBK;

    if (t < NBK) hist[t] = 0;
    __syncthreads();

    // single pass: dst+src pairs (16B loads), hist atomic rank capture.
    // pk = (dlow<<18)|src ; ra = (rank<<9)|bucket  (rank<5120 fits 13 bits)
    unsigned pk[IPT];
    unsigned ra[IPT];
#pragma unroll
    for (int k = 0; k < IPT2; ++k) {
        int e = tile0 + k * (2 * BTH) + 2 * t;
        int d0, d1, s0, s1;
        if (fl) {
            ulonglong2 dd = *(const ulonglong2*)((const long long*)ei + NE + e);
            ulonglong2 ss = *(const ulonglong2*)((const long long*)ei + e);
            d0 = (int)dd.x;
            d1 = (int)dd.y;
            s0 = (int)ss.x;
            s1 = (int)ss.y;
        } else {
            uint2 dd = *(const uint2*)((const int*)ei + NE + e);
            uint2 ss = *(const uint2*)((const int*)ei + e);
            d0 = (int)dd.x;
            d1 = (int)dd.y;
            s0 = (int)ss.x;
            s1 = (int)ss.y;
        }
        int b0 = d0 >> 9, b1 = d1 >> 9;
        int r0 = atomicAdd(&hist[b0], 1);
        int r1 = atomicAdd(&hist[b1], 1);
        pk[2 * k] = ((unsigned)(d0 & 511) << 18) | (unsigned)s0;
        pk[2 * k + 1] = ((unsigned)(d1 & 511) << 18) | (unsigned)s1;
        ra[2 * k] = ((unsigned)r0 << 9) | (unsigned)b0;
        ra[2 * k + 1] = ((unsigned)r1 << 9) | (unsigned)b1;
    }
    __syncthreads();

    // exclusive scan of 392 counts: pair-sum + 64-lane shfl scan + wave combine
    int h0 = 0, h1 = 0, p = 0;
    if (t < NBK / 2) {
        h0 = hist[2 * t];
        h1 = hist[2 * t + 1];
        p = h0 + h1;
    }
    int lane = t & 63;
    int w = t >> 6;
    int incl = p;
#pragma unroll
    for (int off = 1; off < 64; off <<= 1) {
        int v = __shfl_up(incl, off, 64);
        if (lane >= off) incl += v;
    }
    if (lane == 63) wsum[w] = incl;
    __syncthreads();
    int wbase = 0;
#pragma unroll
    for (int ww = 0; ww < BTH / 64; ++ww) wbase += (ww < w) ? wsum[ww] : 0;
    int ex = wbase + incl - p;
    if (t < NBK / 2) {
        lofs[2 * t] = ex;
        lofs[2 * t + 1] = ex + h0;
    }
    if (t < NBK) gofs[t] = atomicAdd(&gcur[(segbase + t) * GSTR], hist[t]);
    __syncthreads();

    // stage from regs at lofs[bucket] + rank (no global loads)
#pragma unroll
    for (int k = 0; k < IPT; ++k) {
        int b = (int)(ra[k] & 511u);
        int r = (int)(ra[k] >> 9);
        stage[lofs[b] + r] = pk[k];
    }
    __syncthreads();

    // coalesced write-out; bucket of slot i via seeded search on lofs
    for (int i = t; i < TILE; i += BTH) {
        int b = (i * 313) >> 12;  // ~ i / 13.06 (mean slots per bucket)
        if (b > NBK - 1) b = NBK - 1;
        while (b < NBK - 1 && lofs[b + 1] <= i) ++b;
        while (lofs[b] > i) --b;
        unsigned pack = stage[i];
        int seg = segbase + b;
        int dest = gofs[b] + (i - lofs[b]);
        if (dest < (seg + 1) * SCAP) {
            binned[dest] = pack;
        } else {  // overflow (never in practice)
            int op = atomicAdd(&gcur[NSEG * GSTR], 1);
            if (op < OVFCAP) {
                int d = (b << 9) | (int)(pack >> 18);
                int s = (int)(pack & 0x3FFFF);
                ovf[op] = ((ull)d << 32) | (unsigned)s;
            }
        }
    }
}

// bucket-local counting sort over 8 sub-segments, key = (dlow<<2)|phase(src).
// count -> scan(2048) -> cursor-atomic scatter (cnt reused as cursor).
// Also computes dinv = rsqrt(degree+1) and packs 4x8-bit phase counts.
__global__ __launch_bounds__(1024, 8) void k_sort(const int* __restrict__ gcur,
                                                  const unsigned* __restrict__ binned,
                                                  const ull* __restrict__ ovf,
                                                  unsigned* __restrict__ csr,
                                                  float* __restrict__ dinv,
                                                  int* __restrict__ rsg,
                                                  unsigned* __restrict__ spl) {
    __shared__ int cnt[2048];
    __shared__ int excl[2048];
    __shared__ int wsum[16];
    int b = blockIdx.x;
    int t = threadIdx.x;
    cnt[t] = 0;
    cnt[t + 1024] = 0;
    __syncthreads();
    int nov = min(gcur[NSEG * GSTR], OVFCAP);

    // pass 1: count keys across the 8 sub-segments (fire-and-forget atomics)
    for (int s = 0; s < NSUB; ++s) {
        int seg = s * NBK + b;
        int sb = seg * SCAP;
        int n = min(gcur[seg * GSTR] - sb, SCAP);
        for (int i = t; i < n; i += 1024) {
            unsigned pack = binned[sb + i];
            unsigned src = pack & 0x3FFFFu;
            int key = ((int)(pack >> 18) << 2) | phase_of(src);
            atomicAdd(&cnt[key], 1);
        }
    }
    __syncthreads();

    // exclusive scan of 2048 counts: pair-sum + 1024-lane scan (16 waves)
    int h0 = cnt[2 * t];
    int h1 = cnt[2 * t + 1];
    int p = h0 + h1;
    int lane = t & 63;
    int w = t >> 6;
    int incl = p;
#pragma unroll
    for (int off = 1; off < 64; off <<= 1) {
        int v = __shfl_up(incl, off, 64);
        if (lane >= off) incl += v;
    }
    if (lane == 63) wsum[w] = incl;
    __syncthreads();
    int wbase = 0;
#pragma unroll
    for (int ww = 0; ww < 16; ++ww) wbase += (ww < w) ? wsum[ww] : 0;
    int ex = wbase + incl - p;
    excl[2 * t] = ex;
    excl[2 * t + 1] = ex + h0;
    __syncthreads();

    if (t < 512) {
        int g = (b << 9) + t;
        if (g < NN) {
            int c0 = cnt[4 * t];
            int c1 = cnt[4 * t + 1];
            int c2 = cnt[4 * t + 2];
            int c3 = cnt[4 * t + 3];
            int extra = 0;
            for (int k = 0; k < nov; ++k) extra += ((int)(ovf[k] >> 32) == g);
            dinv[g] = rsqrtf((float)(c0 + c1 + c2 + c3 + extra) + 1.0f);
            rsg[g] = b * CCAP + excl[4 * t];                 // csr row start (absolute)
            spl[g] = (unsigned)c0 | ((unsigned)c1 << 8) |
                     ((unsigned)c2 << 16) | ((unsigned)c3 << 24);
        }
    }
    __syncthreads();  // stats readers of cnt done before cursor overwrite

    cnt[t] = b * CCAP + excl[t];            // absolute csr cursors
    cnt[t + 1024] = b * CCAP + excl[t + 1024];
    __syncthreads();

    // pass 2: scatter via cursor atomics
    for (int s = 0; s < NSUB; ++s) {
        int seg = s * NBK + b;
        int sb = seg * SCAP;
        int n = min(gcur[seg * GSTR] - sb, SCAP);
        for (int i = t; i < n; i += 1024) {
            unsigned pack = binned[sb + i];
            unsigned src = pack & 0x3FFFFu;
            int key = ((int)(pack >> 18) << 2) | phase_of(src);
            int pos = atomicAdd(&cnt[key], 1);
            csr[pos] = src;
        }
    }
}

// xph[s] = fp16(dinv[s]*x[s]) padded to 16 halves (one aligned 32B row).
__global__ void k_prep(const float* __restrict__ x, const float* __restrict__ dinv,
                       __half* __restrict__ xph) {
    int i = blockIdx.x * blockDim.x + threadIdx.x;
    if (i >= NN * 16) return;
    int node = i >> 4;
    int c = i & 15;
    float v = (c < IC) ? dinv[node] * x[node * IC + c] : 0.0f;
    xph[i] = __float2half(v);
}

// Layer-1 aggregation, phases pbase..pbase+1. q2 = bid&1 -> XCD parity
// affinity: each XCD gathers from ONE 1.6MB phase region. partial buffer
// index = q2 (buffer 0 accumulates phases 0+2, buffer 1 phases 1+3).
// acc=1 (second pass) read-modify-writes. 4 lanes per dst node.
__global__ __launch_bounds__(256) void k_agg1(const int* __restrict__ rsg,
                                              const unsigned* __restrict__ spl,
                                              const unsigned* __restrict__ csr,
                                              const __half* __restrict__ xph,
                                              float* __restrict__ partial,
                                              int pbase, int acc) {
    int t = threadIdx.x;
    int q2 = blockIdx.x & 1;
    int ph = pbase + q2;
    int blk = blockIdx.x >> 1;
    int g = t >> 2;
    int qq = t & 3;
    int i = blk * 64 + g;
    unsigned sp = spl[i];
    int c0 = (int)(sp & 255u);
    int c1 = (int)((sp >> 8) & 255u);
    int c2 = (int)((sp >> 16) & 255u);
    int c3 = (int)(sp >> 24);
    int off = (ph > 0 ? c0 : 0) + (ph > 1 ? c1 : 0) + (ph > 2 ? c2 : 0);
    int len = ph == 0 ? c0 : ph == 1 ? c1 : ph == 2 ? c2 : c3;
    int beg = rsg[i] + off;
    int end = beg + len;

    float ax = 0.0f, ay = 0.0f, az = 0.0f, aw = 0.0f;
    int j = beg;
    for (; j + 1 < end; j += 2) {
        int s0 = csr[j];
        int s1 = csr[j + 1];
        uint2 u0 = *(const uint2*)(xph + (size_t)s0 * 16 + 4 * qq);
        uint2 u1 = *(const uint2*)(xph + (size_t)s1 * 16 + 4 * qq);
        float2 f0 = __half22float2(*(__half2*)&u0.x);
        float2 f1 = __half22float2(*(__half2*)&u0.y);
        float2 f2 = __half22float2(*(__half2*)&u1.x);
        float2 f3 = __half22float2(*(__half2*)&u1.y);
        ax += f0.x + f2.x;
        ay += f0.y + f2.y;
        az += f1.x + f3.x;
        aw += f1.y + f3.y;
    }
    if (j < end) {
        int s0 = csr[j];
        uint2 u0 = *(const uint2*)(xph + (size_t)s0 * 16 + 4 * qq);
        float2 f0 = __half22float2(*(__half2*)&u0.x);
        float2 f1 = __half22float2(*(__half2*)&u0.y);
        ax += f0.x;
        ay += f0.y;
        az += f1.x;
        aw += f1.y;
    }
    f4v r = {ax, ay, az, aw};
    float* dst = partial + ((size_t)q2 * NN + i) * 16 + 4 * qq;
    if (acc) {
        f4v o = __builtin_nontemporal_load((const f4v*)dst);  // zero-reuse stream
        r += o;
    }
    __builtin_nontemporal_store(r, (f4v*)dst);
}

// Sum phase partials + self loop + overflow-list fixup, then the fused MLP.
__global__ __launch_bounds__(256) void k_mlp(const float* __restrict__ partial,
                                             const __half* __restrict__ xph,
                                             const int* __restrict__ gcur,
                                             const ull* __restrict__ ovf,
                                             const float* __restrict__ dinv,
                                             const float* __restrict__ W1,
                                             const float* __restrict__ b1,
                                             const float* __restrict__ W2,
                                             const float* __restrict__ b2,
                                             float2* __restrict__ h2bp,
                                             float2* __restrict__ selfout) {
    __shared__ float sW1[IC * HC];
    __shared__ float sb1[HC];
    __shared__ float sW2[HC * OC];
    __shared__ float sb2[OC];
    int t = threadIdx.x;
    if (t < IC * HC) sW1[t] = W1[t];
    if (t < HC) sb1[t] = b1[t];
    if (t < HC * OC) sW2[t] = W2[t];
    if (t < OC) sb2[t] = b2[t];
    __syncthreads();

    int i = blockIdx.x * 256 + t;
    if (i >= NN) return;

    float dv = dinv[i];
    const float4* p0 = (const float4*)(partial + (size_t)i * 16);
    const float4* p1 = (const float4*)(partial + ((size_t)NN + i) * 16);
    const uint2* sp = (const uint2*)(xph + (size_t)i * 16);

    float agg[16];
#pragma unroll
    for (int c4 = 0; c4 < 4; ++c4) {
        float4 a = p0[c4];
        float4 b = p1[c4];
        uint2 u = sp[c4];
        float2 s0 = __half22float2(*(__half2*)&u.x);
        float2 s1 = __half22float2(*(__half2*)&u.y);
        agg[4 * c4 + 0] = a.x + b.x + s0.x;
        agg[4 * c4 + 1] = a.y + b.y + s0.y;
        agg[4 * c4 + 2] = a.z + b.z + s1.x;
        agg[4 * c4 + 3] = a.w + b.w + s1.y;
    }

    // overflow fixup (nov==0 in practice)
    int nov = min(gcur[NSEG * GSTR], OVFCAP);
    for (int k = 0; k < nov; ++k) {
        ull e = ovf[k];
        if ((int)(e >> 32) == i) {
            int s = (int)(e & 0xFFFFFFFFu);
            for (int c = 0; c < IC; ++c)
                agg[c] += __half2float(xph[(size_t)s * 16 + c]);
        }
    }

    float tt[IC];
#pragma unroll
    for (int c = 0; c < IC; ++c) tt[c] = dv * agg[c];

    float r[HC];
#pragma unroll
    for (int f = 0; f < HC; ++f) {
        float a = sb1[f];
#pragma unroll
        for (int c = 0; c < IC; ++c) a = fmaf(tt[c], sW1[c * HC + f], a);
        r[f] = fmaxf(a, 0.0f);
    }

    float o0 = 0.0f, o1 = 0.0f;
#pragma unroll
    for (int f = 0; f < HC; ++f) {
        o0 = fmaf(r[f], sW2[f * OC + 0], o0);
        o1 = fmaf(r[f], sW2[f * OC + 1], o1);
    }
    h2bp[i] = make_float2(o0 * dv, o1 * dv);  // dinv-prescaled for layer 2
    selfout[i] = make_float2(o0 * dv * dv + sb2[0], o1 * dv * dv + sb2[1]);
}

// layer-2: out[i] = selfout[i] + dinv[i] * (sum h2bp[src] + ovf matches).
// 2 lanes per node (split edge range), shfl_xor combine.
__global__ __launch_bounds__(256) void k_agg2(const int* __restrict__ rsg,
                                              const unsigned* __restrict__ spl,
                                              const unsigned* __restrict__ csr,
                                              const int* __restrict__ gcur,
                                              const ull* __restrict__ ovf,
                                              const float* __restrict__ dinv,
                                              const float2* __restrict__ h2bp,
                                              const float2* __restrict__ selfout,
                                              float2* __restrict__ out) {
    int tt = blockIdx.x * 256 + threadIdx.x;
    int i = tt >> 1;
    int h = tt & 1;
    if (i >= NN) return;
    unsigned sp = spl[i];
    int tot = (int)(sp & 255u) + (int)((sp >> 8) & 255u) +
              (int)((sp >> 16) & 255u) + (int)(sp >> 24);
    int beg = rsg[i];
    int end = beg + tot;
    float ax = 0.0f, ay = 0.0f;
    int j = beg + h;
    for (; j + 2 < end; j += 4) {
        float2 h0 = h2bp[csr[j]];
        float2 h1 = h2bp[csr[j + 2]];
        ax += h0.x + h1.x;
        ay += h0.y + h1.y;
    }
    if (j < end) {
        float2 h0 = h2bp[csr[j]];
        ax += h0.x;
        ay += h0.y;
    }
    ax += __shfl_xor(ax, 1);
    ay += __shfl_xor(ay, 1);
    if (h == 0) {
        // overflow fixup (nov==0 in practice); h2bp already dinv[src]-prescaled
        int nov = min(gcur[NSEG * GSTR], OVFCAP);
        for (int k = 0; k < nov; ++k) {
            ull e = ovf[k];
            if ((int)(e >> 32) == i) {
                float2 hh = h2bp[(int)(e & 0xFFFFFFFFu)];
                ax += hh.x;
                ay += hh.y;
            }
        }
        float dv = dinv[i];
        float2 so = selfout[i];
        out[i] = make_float2(so.x + dv * ax, so.y + dv * ay);
    }
}

extern "C" void kernel_launch(void* const* d_in, const int* in_sizes, int n_in,
                              void* d_out, int out_size, void* d_ws, size_t ws_size,
                              hipStream_t stream) {
    const float* x = (const float*)d_in[0];
    const void* ei = d_in[1];
    // d_in[2] = edge_attr (unused)
    const float* W1 = (const float*)d_in[3];
    const float* b1 = (const float*)d_in[4];
    const float* W2 = (const float*)d_in[5];
    const float* b2 = (const float*)d_in[6];
    float* out = (float*)d_out;

    ull* ovf = (ull*)d_ws;                              // OVFCAP       (0.5MB)
    int* gcur = (int*)(ovf + OVFCAP);                   // (NSEG+1)*16 ints (200KB)
    int* flag = gcur + (NSEG + 1) * GSTR;               // 4
    int* rsg = flag + 4;                                // NN
    unsigned* spl = (unsigned*)(rsg + NN);              // NN
    float* dinv = (float*)(spl + NN);                   // NN
    __half* xph = (__half*)(dinv + NN);                 // NN*16 halves (6.4MB)
    float2* h2bp = (float2*)(xph + (size_t)NN * 16);    // NN
    float2* selfout = h2bp + NN;                        // NN
    unsigned* binned = (unsigned*)(selfout + NN);       // NSEG*SCAP    (35.3MB)
    float* partial = (float*)binned;                    // 2*NN*16 f32 (25.6MB), overlays
                                                        // binned (dead after k_sort)
    unsigned* csr = binned + (size_t)NSEG * SCAP;       // NBK*CCAP     (35.3MB)

    k_init<<<(NSEG + 1 + 255) / 256, 256, 0, stream>>>(gcur, ei, flag);
    k_binA<<<NTILE, BTH, 0, stream>>>(ei, flag, gcur, binned, ovf);
    k_sort<<<NBK, 1024, 0, stream>>>(gcur, binned, ovf, csr, dinv, rsg, spl);
    k_prep<<<(NN * 16 + 255) / 256, 256, 0, stream>>>(x, dinv, xph);
    k_agg1<<<2 * NAGG, 256, 0, stream>>>(rsg, spl, csr, xph, partial, 0, 0);
    k_agg1<<<2 * NAGG, 256, 0, stream>>>(rsg, spl, csr, xph, partial, 2, 1);
    k_mlp<<<NB, 256, 0, stream>>>(partial, xph, gcur, ovf, dinv, W1, b1, W2, b2,
                                  h2bp, selfout);
    k_agg2<<<(NN * 2 + 255) / 256, 256, 0, stream>>>(rsg, spl, csr, gcur, ovf, dinv,
                                                     h2bp, selfout, (float2*)out);
}

// Round 5
// 323.763 us; speedup vs baseline: 1.2596x; 1.0837x over previous
//
#include <hip/hip_runtime.h>
#include <hip/hip_fp16.h>

// GCN 2-layer: N=200000, E=6400000, 14 -> 16(relu) -> 2.
// Round 17: k_sort write-amplification fix. WRITE was 130MB vs 25.6MB logical
// (5x): cursor-atomic 4B scatters over an 88KB bucket region fill each 64B
// line slowly while the binned read stream flushes L2 -> ~5 partial
// writebacks per line. Fix = binA's own recipe applied to sort:
//   - single pass over binned: rank captured from cnt atomic, (src, rank|key)
//     held in regs (8 segs x 3 slots, statically indexed -> no scratch);
//   - scatter into an 88KB LDS stage at excl[key]+rank;
//   - stream the bucket out as coalesced uint4 -> every csr line written once.
//   LDS ~104KB -> 1 block/CU (16 waves, ~= previous occupancy) at 1/3 the
//   global traffic. Second binned read + second atomic pass deleted.
// Pipeline: init -> binA -> sort(+dinv) -> prep -> agg1A -> agg1B -> mlp -> agg2.

constexpr int NN = 200000;
constexpr int NE = 6400000;
constexpr int IC = 14;
constexpr int HC = 16;
constexpr int OC = 2;

constexpr int NBK = 392;                   // buckets of 512 dst nodes
constexpr int NSUB = 8;                    // sub-segments per bucket (bid&7)
constexpr int SCAP = 2816;                 // per (sub,bucket) cap: mean 2058 + 16.7 sigma
constexpr int NSEG = NSUB * NBK;           // 3136 segments
constexpr int CCAP = NSUB * SCAP;          // 22528 csr per-bucket capacity
constexpr int SPT = (SCAP + 1023) / 1024;  // 3 reg slots per (thread, segment)
constexpr int TILE = 5120;                 // edges per binA tile
constexpr int BTH = 512;                   // binA threads
constexpr int IPT = TILE / BTH;            // 10
constexpr int IPT2 = IPT / 2;              // 5 pair-loads per thread
constexpr int NTILE = NE / TILE;           // 1250
constexpr int OVFCAP = 65536;
constexpr int NB = (NN + 255) / 256;       // 782
constexpr int NAGG = NN / 64;              // 3125 blocks per phase-pair half
constexpr int GSTR = 16;                   // gcur stride: 1 counter per 64B line

typedef unsigned long long ull;
typedef float f4v __attribute__((ext_vector_type(4)));

__device__ __forceinline__ int phase_of(unsigned src) {
    return src >= 100000u ? (src >= 150000u ? 3 : 2) : (src >= 50000u ? 1 : 0);
}

// init gcur (padded) + ovf counter + dtype flag
__global__ void k_init(int* __restrict__ gcur, const void* __restrict__ ei,
                       int* __restrict__ flag) {
    int i = blockIdx.x * blockDim.x + threadIdx.x;
    if (i < NSEG) gcur[i * GSTR] = i * SCAP;
    else if (i == NSEG) gcur[i * GSTR] = 0;  // overflow counter
    if (i == 500) {  // one thread sniffs edge dtype
        const ull* p = (const ull*)ei;
        ull acc = 0ULL;
        for (int k = 0; k < 64; ++k) acc |= (p[k] >> 32);
        *flag = (acc == 0ULL) ? 1 : 0;  // 1 => int64 indices, 0 => int32
    }
}

// Bin edges by dst>>9 into per-(sub,bucket) global segments, sub = bid&7.
// Single pass over edges: dst+src pair-loaded, rank captured from the
// histogram atomic, both held in regs across the scan. LDS-staged for
// coalesced segment write-out.
__global__ __launch_bounds__(BTH, 8) void k_binA(const void* __restrict__ ei,
                                                 const int* __restrict__ flag,
                                                 int* __restrict__ gcur,
                                                 unsigned* __restrict__ binned,
                                                 ull* __restrict__ ovf) {
    __shared__ int hist[NBK];
    __shared__ int lofs[NBK];
    __shared__ int gofs[NBK];
    __shared__ int wsum[BTH / 64];
    __shared__ unsigned stage[TILE];

    int t = threadIdx.x;
    int fl = *flag;
    int tile0 = blockIdx.x * TILE;
    int segbase = (blockIdx.x & (NSUB - 1)) * NBK;

    if (t < NBK) hist[t] = 0;
    __syncthreads();

    // single pass: dst+src pairs (16B loads), hist atomic rank capture.
    // pk = (dlow<<18)|src ; ra = (rank<<9)|bucket  (rank<5120 fits 13 bits)
    unsigned pk[IPT];
    unsigned ra[IPT];
#pragma unroll
    for (int k = 0; k < IPT2; ++k) {
        int e = tile0 + k * (2 * BTH) + 2 * t;
        int d0, d1, s0, s1;
        if (fl) {
            ulonglong2 dd = *(const ulonglong2*)((const long long*)ei + NE + e);
            ulonglong2 ss = *(const ulonglong2*)((const long long*)ei + e);
            d0 = (int)dd.x;
            d1 = (int)dd.y;
            s0 = (int)ss.x;
            s1 = (int)ss.y;
        } else {
            uint2 dd = *(const uint2*)((const int*)ei + NE + e);
            uint2 ss = *(const uint2*)((const int*)ei + e);
            d0 = (int)dd.x;
            d1 = (int)dd.y;
            s0 = (int)ss.x;
            s1 = (int)ss.y;
        }
        int b0 = d0 >> 9, b1 = d1 >> 9;
        int r0 = atomicAdd(&hist[b0], 1);
        int r1 = atomicAdd(&hist[b1], 1);
        pk[2 * k] = ((unsigned)(d0 & 511) << 18) | (unsigned)s0;
        pk[2 * k + 1] = ((unsigned)(d1 & 511) << 18) | (unsigned)s1;
        ra[2 * k] = ((unsigned)r0 << 9) | (unsigned)b0;
        ra[2 * k + 1] = ((unsigned)r1 << 9) | (unsigned)b1;
    }
    __syncthreads();

    // exclusive scan of 392 counts: pair-sum + 64-lane shfl scan + wave combine
    int h0 = 0, h1 = 0, p = 0;
    if (t < NBK / 2) {
        h0 = hist[2 * t];
        h1 = hist[2 * t + 1];
        p = h0 + h1;
    }
    int lane = t & 63;
    int w = t >> 6;
    int incl = p;
#pragma unroll
    for (int off = 1; off < 64; off <<= 1) {
        int v = __shfl_up(incl, off, 64);
        if (lane >= off) incl += v;
    }
    if (lane == 63) wsum[w] = incl;
    __syncthreads();
    int wbase = 0;
#pragma unroll
    for (int ww = 0; ww < BTH / 64; ++ww) wbase += (ww < w) ? wsum[ww] : 0;
    int ex = wbase + incl - p;
    if (t < NBK / 2) {
        lofs[2 * t] = ex;
        lofs[2 * t + 1] = ex + h0;
    }
    if (t < NBK) gofs[t] = atomicAdd(&gcur[(segbase + t) * GSTR], hist[t]);
    __syncthreads();

    // stage from regs at lofs[bucket] + rank (no global loads)
#pragma unroll
    for (int k = 0; k < IPT; ++k) {
        int b = (int)(ra[k] & 511u);
        int r = (int)(ra[k] >> 9);
        stage[lofs[b] + r] = pk[k];
    }
    __syncthreads();

    // coalesced write-out; bucket of slot i via seeded search on lofs
    for (int i = t; i < TILE; i += BTH) {
        int b = (i * 313) >> 12;  // ~ i / 13.06 (mean slots per bucket)
        if (b > NBK - 1) b = NBK - 1;
        while (b < NBK - 1 && lofs[b + 1] <= i) ++b;
        while (lofs[b] > i) --b;
        unsigned pack = stage[i];
        int seg = segbase + b;
        int dest = gofs[b] + (i - lofs[b]);
        if (dest < (seg + 1) * SCAP) {
            binned[dest] = pack;
        } else {  // overflow (never in practice)
            int op = atomicAdd(&gcur[NSEG * GSTR], 1);
            if (op < OVFCAP) {
                int d = (b << 9) | (int)(pack >> 18);
                int s = (int)(pack & 0x3FFFF);
                ovf[op] = ((ull)d << 32) | (unsigned)s;
            }
        }
    }
}

// bucket-local counting sort over 8 sub-segments, key = (dlow<<2)|phase(src).
// Single pass: rank captured from cnt atomic, (src, rank|key) in regs
// (static 8x3 slots); scatter into LDS stage at excl[key]+rank; coalesced
// uint4 write-out (every csr line written once -> no write amplification).
// Also computes dinv = rsqrt(degree+1) and packs 4x8-bit phase counts.
__global__ __launch_bounds__(1024, 4) void k_sort(const int* __restrict__ gcur,
                                                  const unsigned* __restrict__ binned,
                                                  const ull* __restrict__ ovf,
                                                  unsigned* __restrict__ csr,
                                                  float* __restrict__ dinv,
                                                  int* __restrict__ rsg,
                                                  unsigned* __restrict__ spl) {
    __shared__ int cnt[2048];
    __shared__ int excl[2048];
    __shared__ int wsum[16];
    __shared__ int nseg[NSUB];
    __shared__ unsigned stage[CCAP];      // 88KB sorted bucket staging
    int b = blockIdx.x;
    int t = threadIdx.x;
    cnt[t] = 0;
    cnt[t + 1024] = 0;
    if (t < NSUB) {
        int seg = t * NBK + b;
        nseg[t] = min(gcur[seg * GSTR] - seg * SCAP, SCAP);
    }
    __syncthreads();
    int nov = min(gcur[NSEG * GSTR], OVFCAP);

    // single pass: load + key + rank capture; held in regs (static indexing)
    unsigned srcv[NSUB * SPT];
    unsigned rkv[NSUB * SPT];
#pragma unroll
    for (int s = 0; s < NSUB; ++s) {
        int n = nseg[s];
        int sb = (s * NBK + b) * SCAP;
#pragma unroll
        for (int k = 0; k < SPT; ++k) {
            int i = k * 1024 + t;
            rkv[s * SPT + k] = 0xFFFFFFFFu;
            if (i < n) {
                unsigned pack = binned[sb + i];
                unsigned src = pack & 0x3FFFFu;
                int key = ((int)(pack >> 18) << 2) | phase_of(src);
                int r = atomicAdd(&cnt[key], 1);
                srcv[s * SPT + k] = src;
                rkv[s * SPT + k] = ((unsigned)r << 11) | (unsigned)key;
            }
        }
    }
    __syncthreads();

    // exclusive scan of 2048 counts: pair-sum + 1024-lane scan (16 waves)
    int h0 = cnt[2 * t];
    int h1 = cnt[2 * t + 1];
    int p = h0 + h1;
    int lane = t & 63;
    int w = t >> 6;
    int incl = p;
#pragma unroll
    for (int off = 1; off < 64; off <<= 1) {
        int v = __shfl_up(incl, off, 64);
        if (lane >= off) incl += v;
    }
    if (lane == 63) wsum[w] = incl;
    __syncthreads();
    int wbase = 0;
#pragma unroll
    for (int ww = 0; ww < 16; ++ww) wbase += (ww < w) ? wsum[ww] : 0;
    int ex = wbase + incl - p;
    excl[2 * t] = ex;
    excl[2 * t + 1] = ex + h0;
    __syncthreads();

    // scatter into LDS stage (bucket-relative positions)
#pragma unroll
    for (int c = 0; c < NSUB * SPT; ++c) {
        unsigned rk = rkv[c];
        if (rk != 0xFFFFFFFFu) {
            int key = (int)(rk & 0x7FFu);
            int r = (int)(rk >> 11);
            stage[excl[key] + r] = srcv[c];
        }
    }

    // per-node stats (cnt/excl are stable; independent of stage)
    if (t < 512) {
        int g = (b << 9) + t;
        if (g < NN) {
            int c0 = cnt[4 * t];
            int c1 = cnt[4 * t + 1];
            int c2 = cnt[4 * t + 2];
            int c3 = cnt[4 * t + 3];
            int extra = 0;
            for (int k = 0; k < nov; ++k) extra += ((int)(ovf[k] >> 32) == g);
            dinv[g] = rsqrtf((float)(c0 + c1 + c2 + c3 + extra) + 1.0f);
            rsg[g] = b * CCAP + excl[4 * t];                 // csr row start (absolute)
            spl[g] = (unsigned)c0 | ((unsigned)c1 << 8) |
                     ((unsigned)c2 << 16) | ((unsigned)c3 << 24);
        }
    }
    __syncthreads();

    // coalesced uint4 write-out (pad to 16B; garbage pad stays in-bucket)
    int total = excl[2047] + cnt[2047];
    int tot4 = (total + 3) >> 2;
    const uint4* st4 = (const uint4*)stage;
    uint4* csr4 = (uint4*)(csr + (size_t)b * CCAP);
#pragma unroll
    for (int k = 0; k < (CCAP / 4 + 1023) / 1024; ++k) {
        int i4 = k * 1024 + t;
        if (i4 < tot4) csr4[i4] = st4[i4];
    }
}

// xph[s] = fp16(dinv[s]*x[s]) padded to 16 halves (one aligned 32B row).
__global__ void k_prep(const float* __restrict__ x, const float* __restrict__ dinv,
                       __half* __restrict__ xph) {
    int i = blockIdx.x * blockDim.x + threadIdx.x;
    if (i >= NN * 16) return;
    int node = i >> 4;
    int c = i & 15;
    float v = (c < IC) ? dinv[node] * x[node * IC + c] : 0.0f;
    xph[i] = __float2half(v);
}

// Layer-1 aggregation, phases pbase..pbase+1. q2 = bid&1 -> XCD parity
// affinity: each XCD gathers from ONE 1.6MB phase region. partial buffer
// index = q2 (buffer 0 accumulates phases 0+2, buffer 1 phases 1+3).
// acc=1 (second pass) read-modify-writes. 4 lanes per dst node.
__global__ __launch_bounds__(256) void k_agg1(const int* __restrict__ rsg,
                                              const unsigned* __restrict__ spl,
                                              const unsigned* __restrict__ csr,
                                              const __half* __restrict__ xph,
                                              float* __restrict__ partial,
                                              int pbase, int acc) {
    int t = threadIdx.x;
    int q2 = blockIdx.x & 1;
    int ph = pbase + q2;
    int blk = blockIdx.x >> 1;
    int g = t >> 2;
    int qq = t & 3;
    int i = blk * 64 + g;
    unsigned sp = spl[i];
    int c0 = (int)(sp & 255u);
    int c1 = (int)((sp >> 8) & 255u);
    int c2 = (int)((sp >> 16) & 255u);
    int c3 = (int)(sp >> 24);
    int off = (ph > 0 ? c0 : 0) + (ph > 1 ? c1 : 0) + (ph > 2 ? c2 : 0);
    int len = ph == 0 ? c0 : ph == 1 ? c1 : ph == 2 ? c2 : c3;
    int beg = rsg[i] + off;
    int end = beg + len;

    float ax = 0.0f, ay = 0.0f, az = 0.0f, aw = 0.0f;
    int j = beg;
    for (; j + 1 < end; j += 2) {
        int s0 = csr[j];
        int s1 = csr[j + 1];
        uint2 u0 = *(const uint2*)(xph + (size_t)s0 * 16 + 4 * qq);
        uint2 u1 = *(const uint2*)(xph + (size_t)s1 * 16 + 4 * qq);
        float2 f0 = __half22float2(*(__half2*)&u0.x);
        float2 f1 = __half22float2(*(__half2*)&u0.y);
        float2 f2 = __half22float2(*(__half2*)&u1.x);
        float2 f3 = __half22float2(*(__half2*)&u1.y);
        ax += f0.x + f2.x;
        ay += f0.y + f2.y;
        az += f1.x + f3.x;
        aw += f1.y + f3.y;
    }
    if (j < end) {
        int s0 = csr[j];
        uint2 u0 = *(const uint2*)(xph + (size_t)s0 * 16 + 4 * qq);
        float2 f0 = __half22float2(*(__half2*)&u0.x);
        float2 f1 = __half22float2(*(__half2*)&u0.y);
        ax += f0.x;
        ay += f0.y;
        az += f1.x;
        aw += f1.y;
    }
    f4v r = {ax, ay, az, aw};
    float* dst = partial + ((size_t)q2 * NN + i) * 16 + 4 * qq;
    if (acc) {
        f4v o = __builtin_nontemporal_load((const f4v*)dst);  // zero-reuse stream
        r += o;
    }
    __builtin_nontemporal_store(r, (f4v*)dst);
}

// Sum phase partials + self loop + overflow-list fixup, then the fused MLP.
__global__ __launch_bounds__(256) void k_mlp(const float* __restrict__ partial,
                                             const __half* __restrict__ xph,
                                             const int* __restrict__ gcur,
                                             const ull* __restrict__ ovf,
                                             const float* __restrict__ dinv,
                                             const float* __restrict__ W1,
                                             const float* __restrict__ b1,
                                             const float* __restrict__ W2,
                                             const float* __restrict__ b2,
                                             float2* __restrict__ h2bp,
                                             float2* __restrict__ selfout) {
    __shared__ float sW1[IC * HC];
    __shared__ float sb1[HC];
    __shared__ float sW2[HC * OC];
    __shared__ float sb2[OC];
    int t = threadIdx.x;
    if (t < IC * HC) sW1[t] = W1[t];
    if (t < HC) sb1[t] = b1[t];
    if (t < HC * OC) sW2[t] = W2[t];
    if (t < OC) sb2[t] = b2[t];
    __syncthreads();

    int i = blockIdx.x * 256 + t;
    if (i >= NN) return;

    float dv = dinv[i];
    const float4* p0 = (const float4*)(partial + (size_t)i * 16);
    const float4* p1 = (const float4*)(partial + ((size_t)NN + i) * 16);
    const uint2* sp = (const uint2*)(xph + (size_t)i * 16);

    float agg[16];
#pragma unroll
    for (int c4 = 0; c4 < 4; ++c4) {
        float4 a = p0[c4];
        float4 b = p1[c4];
        uint2 u = sp[c4];
        float2 s0 = __half22float2(*(__half2*)&u.x);
        float2 s1 = __half22float2(*(__half2*)&u.y);
        agg[4 * c4 + 0] = a.x + b.x + s0.x;
        agg[4 * c4 + 1] = a.y + b.y + s0.y;
        agg[4 * c4 + 2] = a.z + b.z + s1.x;
        agg[4 * c4 + 3] = a.w + b.w + s1.y;
    }

    // overflow fixup (nov==0 in practice)
    int nov = min(gcur[NSEG * GSTR], OVFCAP);
    for (int k = 0; k < nov; ++k) {
        ull e = ovf[k];
        if ((int)(e >> 32) == i) {
            int s = (int)(e & 0xFFFFFFFFu);
            for (int c = 0; c < IC; ++c)
                agg[c] += __half2float(xph[(size_t)s * 16 + c]);
        }
    }

    float tt[IC];
#pragma unroll
    for (int c = 0; c < IC; ++c) tt[c] = dv * agg[c];

    float r[HC];
#pragma unroll
    for (int f = 0; f < HC; ++f) {
        float a = sb1[f];
#pragma unroll
        for (int c = 0; c < IC; ++c) a = fmaf(tt[c], sW1[c * HC + f], a);
        r[f] = fmaxf(a, 0.0f);
    }

    float o0 = 0.0f, o1 = 0.0f;
#pragma unroll
    for (int f = 0; f < HC; ++f) {
        o0 = fmaf(r[f], sW2[f * OC + 0], o0);
        o1 = fmaf(r[f], sW2[f * OC + 1], o1);
    }
    h2bp[i] = make_float2(o0 * dv, o1 * dv);  // dinv-prescaled for layer 2
    selfout[i] = make_float2(o0 * dv * dv + sb2[0], o1 * dv * dv + sb2[1]);
}

// layer-2: out[i] = selfout[i] + dinv[i] * (sum h2bp[src] + ovf matches).
// 2 lanes per node (split edge range), shfl_xor combine.
__global__ __launch_bounds__(256) void k_agg2(const int* __restrict__ rsg,
                                              const unsigned* __restrict__ spl,
                                              const unsigned* __restrict__ csr,
                                              const int* __restrict__ gcur,
                                              const ull* __restrict__ ovf,
                                              const float* __restrict__ dinv,
                                              const float2* __restrict__ h2bp,
                                              const float2* __restrict__ selfout,
                                              float2* __restrict__ out) {
    int tt = blockIdx.x * 256 + threadIdx.x;
    int i = tt >> 1;
    int h = tt & 1;
    if (i >= NN) return;
    unsigned sp = spl[i];
    int tot = (int)(sp & 255u) + (int)((sp >> 8) & 255u) +
              (int)((sp >> 16) & 255u) + (int)(sp >> 24);
    int beg = rsg[i];
    int end = beg + tot;
    float ax = 0.0f, ay = 0.0f;
    int j = beg + h;
    for (; j + 2 < end; j += 4) {
        float2 h0 = h2bp[csr[j]];
        float2 h1 = h2bp[csr[j + 2]];
        ax += h0.x + h1.x;
        ay += h0.y + h1.y;
    }
    if (j < end) {
        float2 h0 = h2bp[csr[j]];
        ax += h0.x;
        ay += h0.y;
    }
    ax += __shfl_xor(ax, 1);
    ay += __shfl_xor(ay, 1);
    if (h == 0) {
        // overflow fixup (nov==0 in practice); h2bp already dinv[src]-prescaled
        int nov = min(gcur[NSEG * GSTR], OVFCAP);
        for (int k = 0; k < nov; ++k) {
            ull e = ovf[k];
            if ((int)(e >> 32) == i) {
                float2 hh = h2bp[(int)(e & 0xFFFFFFFFu)];
                ax += hh.x;
                ay += hh.y;
            }
        }
        float dv = dinv[i];
        float2 so = selfout[i];
        out[i] = make_float2(so.x + dv * ax, so.y + dv * ay);
    }
}

extern "C" void kernel_launch(void* const* d_in, const int* in_sizes, int n_in,
                              void* d_out, int out_size, void* d_ws, size_t ws_size,
                              hipStream_t stream) {
    const float* x = (const float*)d_in[0];
    const void* ei = d_in[1];
    // d_in[2] = edge_attr (unused)
    const float* W1 = (const float*)d_in[3];
    const float* b1 = (const float*)d_in[4];
    const float* W2 = (const float*)d_in[5];
    const float* b2 = (const float*)d_in[6];
    float* out = (float*)d_out;

    ull* ovf = (ull*)d_ws;                              // OVFCAP       (0.5MB)
    int* gcur = (int*)(ovf + OVFCAP);                   // (NSEG+1)*16 ints (200KB)
    int* flag = gcur + (NSEG + 1) * GSTR;               // 4
    int* rsg = flag + 4;                                // NN
    unsigned* spl = (unsigned*)(rsg + NN);              // NN
    float* dinv = (float*)(spl + NN);                   // NN
    __half* xph = (__half*)(dinv + NN);                 // NN*16 halves (6.4MB)
    float2* h2bp = (float2*)(xph + (size_t)NN * 16);    // NN
    float2* selfout = h2bp + NN;                        // NN
    unsigned* binned = (unsigned*)(selfout + NN);       // NSEG*SCAP    (35.3MB)
    float* partial = (float*)binned;                    // 2*NN*16 f32 (25.6MB), overlays
                                                        // binned (dead after k_sort)
    unsigned* csr = binned + (size_t)NSEG * SCAP;       // NBK*CCAP     (35.3MB)

    k_init<<<(NSEG + 1 + 255) / 256, 256, 0, stream>>>(gcur, ei, flag);
    k_binA<<<NTILE, BTH, 0, stream>>>(ei, flag, gcur, binned, ovf);
    k_sort<<<NBK, 1024, 0, stream>>>(gcur, binned, ovf, csr, dinv, rsg, spl);
    k_prep<<<(NN * 16 + 255) / 256, 256, 0, stream>>>(x, dinv, xph);
    k_agg1<<<2 * NAGG, 256, 0, stream>>>(rsg, spl, csr, xph, partial, 0, 0);
    k_agg1<<<2 * NAGG, 256, 0, stream>>>(rsg, spl, csr, xph, partial, 2, 1);
    k_mlp<<<NB, 256, 0, stream>>>(partial, xph, gcur, ovf, dinv, W1, b1, W2, b2,
                                  h2bp, selfout);
    k_agg2<<<(NN * 2 + 255) / 256, 256, 0, stream>>>(rsg, spl, csr, gcur, ovf, dinv,
                                                     h2bp, selfout, (float2*)out);
}

// Round 6
// 308.453 us; speedup vs baseline: 1.3221x; 1.0496x over previous
//
#include <hip/hip_runtime.h>
#include <hip/hip_fp16.h>

// GCN 2-layer: N=200000, E=6400000, 14 -> 16(relu) -> 2.
// Round 18: k_agg2 latency fix. agg2 was 54us at 12% HBM / 3% VALU: 2 lanes
// per node x ~8 sequential dependent csr->h2bp gather steps = pure latency
// chain. Now 4 lanes per node (stride-4 interleave) + 2-way unroll:
// chain ~4 steps, 2x the loads in flight, grid 2x (3125 blocks) for TLP.
// Combine via shfl_xor(1,2). csr loads stay normal (L1 line reuse across
// adjacent lanes -- nt would kill it, round-14 lesson).
// Pipeline: init -> binA -> sort(+dinv) -> prep -> agg1A -> agg1B -> mlp -> agg2.

constexpr int NN = 200000;
constexpr int NE = 6400000;
constexpr int IC = 14;
constexpr int HC = 16;
constexpr int OC = 2;

constexpr int NBK = 392;                   // buckets of 512 dst nodes
constexpr int NSUB = 8;                    // sub-segments per bucket (bid&7)
constexpr int SCAP = 2816;                 // per (sub,bucket) cap: mean 2058 + 16.7 sigma
constexpr int NSEG = NSUB * NBK;           // 3136 segments
constexpr int CCAP = NSUB * SCAP;          // 22528 csr per-bucket capacity
constexpr int SPT = (SCAP + 1023) / 1024;  // 3 reg slots per (thread, segment)
constexpr int TILE = 5120;                 // edges per binA tile
constexpr int BTH = 512;                   // binA threads
constexpr int IPT = TILE / BTH;            // 10
constexpr int IPT2 = IPT / 2;              // 5 pair-loads per thread
constexpr int NTILE = NE / TILE;           // 1250
constexpr int OVFCAP = 65536;
constexpr int NB = (NN + 255) / 256;       // 782
constexpr int NAGG = NN / 64;              // 3125 blocks per phase-pair half
constexpr int GSTR = 16;                   // gcur stride: 1 counter per 64B line

typedef unsigned long long ull;
typedef float f4v __attribute__((ext_vector_type(4)));

__device__ __forceinline__ int phase_of(unsigned src) {
    return src >= 100000u ? (src >= 150000u ? 3 : 2) : (src >= 50000u ? 1 : 0);
}

// init gcur (padded) + ovf counter + dtype flag
__global__ void k_init(int* __restrict__ gcur, const void* __restrict__ ei,
                       int* __restrict__ flag) {
    int i = blockIdx.x * blockDim.x + threadIdx.x;
    if (i < NSEG) gcur[i * GSTR] = i * SCAP;
    else if (i == NSEG) gcur[i * GSTR] = 0;  // overflow counter
    if (i == 500) {  // one thread sniffs edge dtype
        const ull* p = (const ull*)ei;
        ull acc = 0ULL;
        for (int k = 0; k < 64; ++k) acc |= (p[k] >> 32);
        *flag = (acc == 0ULL) ? 1 : 0;  // 1 => int64 indices, 0 => int32
    }
}

// Bin edges by dst>>9 into per-(sub,bucket) global segments, sub = bid&7.
// Single pass over edges: dst+src pair-loaded, rank captured from the
// histogram atomic, both held in regs across the scan. LDS-staged for
// coalesced segment write-out.
__global__ __launch_bounds__(BTH, 8) void k_binA(const void* __restrict__ ei,
                                                 const int* __restrict__ flag,
                                                 int* __restrict__ gcur,
                                                 unsigned* __restrict__ binned,
                                                 ull* __restrict__ ovf) {
    __shared__ int hist[NBK];
    __shared__ int lofs[NBK];
    __shared__ int gofs[NBK];
    __shared__ int wsum[BTH / 64];
    __shared__ unsigned stage[TILE];

    int t = threadIdx.x;
    int fl = *flag;
    int tile0 = blockIdx.x * TILE;
    int segbase = (blockIdx.x & (NSUB - 1)) * NBK;

    if (t < NBK) hist[t] = 0;
    __syncthreads();

    // single pass: dst+src pairs (16B loads), hist atomic rank capture.
    // pk = (dlow<<18)|src ; ra = (rank<<9)|bucket  (rank<5120 fits 13 bits)
    unsigned pk[IPT];
    unsigned ra[IPT];
#pragma unroll
    for (int k = 0; k < IPT2; ++k) {
        int e = tile0 + k * (2 * BTH) + 2 * t;
        int d0, d1, s0, s1;
        if (fl) {
            ulonglong2 dd = *(const ulonglong2*)((const long long*)ei + NE + e);
            ulonglong2 ss = *(const ulonglong2*)((const long long*)ei + e);
            d0 = (int)dd.x;
            d1 = (int)dd.y;
            s0 = (int)ss.x;
            s1 = (int)ss.y;
        } else {
            uint2 dd = *(const uint2*)((const int*)ei + NE + e);
            uint2 ss = *(const uint2*)((const int*)ei + e);
            d0 = (int)dd.x;
            d1 = (int)dd.y;
            s0 = (int)ss.x;
            s1 = (int)ss.y;
        }
        int b0 = d0 >> 9, b1 = d1 >> 9;
        int r0 = atomicAdd(&hist[b0], 1);
        int r1 = atomicAdd(&hist[b1], 1);
        pk[2 * k] = ((unsigned)(d0 & 511) << 18) | (unsigned)s0;
        pk[2 * k + 1] = ((unsigned)(d1 & 511) << 18) | (unsigned)s1;
        ra[2 * k] = ((unsigned)r0 << 9) | (unsigned)b0;
        ra[2 * k + 1] = ((unsigned)r1 << 9) | (unsigned)b1;
    }
    __syncthreads();

    // exclusive scan of 392 counts: pair-sum + 64-lane shfl scan + wave combine
    int h0 = 0, h1 = 0, p = 0;
    if (t < NBK / 2) {
        h0 = hist[2 * t];
        h1 = hist[2 * t + 1];
        p = h0 + h1;
    }
    int lane = t & 63;
    int w = t >> 6;
    int incl = p;
#pragma unroll
    for (int off = 1; off < 64; off <<= 1) {
        int v = __shfl_up(incl, off, 64);
        if (lane >= off) incl += v;
    }
    if (lane == 63) wsum[w] = incl;
    __syncthreads();
    int wbase = 0;
#pragma unroll
    for (int ww = 0; ww < BTH / 64; ++ww) wbase += (ww < w) ? wsum[ww] : 0;
    int ex = wbase + incl - p;
    if (t < NBK / 2) {
        lofs[2 * t] = ex;
        lofs[2 * t + 1] = ex + h0;
    }
    if (t < NBK) gofs[t] = atomicAdd(&gcur[(segbase + t) * GSTR], hist[t]);
    __syncthreads();

    // stage from regs at lofs[bucket] + rank (no global loads)
#pragma unroll
    for (int k = 0; k < IPT; ++k) {
        int b = (int)(ra[k] & 511u);
        int r = (int)(ra[k] >> 9);
        stage[lofs[b] + r] = pk[k];
    }
    __syncthreads();

    // coalesced write-out; bucket of slot i via seeded search on lofs
    for (int i = t; i < TILE; i += BTH) {
        int b = (i * 313) >> 12;  // ~ i / 13.06 (mean slots per bucket)
        if (b > NBK - 1) b = NBK - 1;
        while (b < NBK - 1 && lofs[b + 1] <= i) ++b;
        while (lofs[b] > i) --b;
        unsigned pack = stage[i];
        int seg = segbase + b;
        int dest = gofs[b] + (i - lofs[b]);
        if (dest < (seg + 1) * SCAP) {
            binned[dest] = pack;
        } else {  // overflow (never in practice)
            int op = atomicAdd(&gcur[NSEG * GSTR], 1);
            if (op < OVFCAP) {
                int d = (b << 9) | (int)(pack >> 18);
                int s = (int)(pack & 0x3FFFF);
                ovf[op] = ((ull)d << 32) | (unsigned)s;
            }
        }
    }
}

// bucket-local counting sort over 8 sub-segments, key = (dlow<<2)|phase(src).
// Single pass: rank captured from cnt atomic, (src, rank|key) in regs
// (static 8x3 slots); scatter into LDS stage at excl[key]+rank; coalesced
// uint4 write-out (every csr line written once -> no write amplification).
// Also computes dinv = rsqrt(degree+1) and packs 4x8-bit phase counts.
__global__ __launch_bounds__(1024, 4) void k_sort(const int* __restrict__ gcur,
                                                  const unsigned* __restrict__ binned,
                                                  const ull* __restrict__ ovf,
                                                  unsigned* __restrict__ csr,
                                                  float* __restrict__ dinv,
                                                  int* __restrict__ rsg,
                                                  unsigned* __restrict__ spl) {
    __shared__ int cnt[2048];
    __shared__ int excl[2048];
    __shared__ int wsum[16];
    __shared__ int nseg[NSUB];
    __shared__ unsigned stage[CCAP];      // 88KB sorted bucket staging
    int b = blockIdx.x;
    int t = threadIdx.x;
    cnt[t] = 0;
    cnt[t + 1024] = 0;
    if (t < NSUB) {
        int seg = t * NBK + b;
        nseg[t] = min(gcur[seg * GSTR] - seg * SCAP, SCAP);
    }
    __syncthreads();
    int nov = min(gcur[NSEG * GSTR], OVFCAP);

    // single pass: load + key + rank capture; held in regs (static indexing)
    unsigned srcv[NSUB * SPT];
    unsigned rkv[NSUB * SPT];
#pragma unroll
    for (int s = 0; s < NSUB; ++s) {
        int n = nseg[s];
        int sb = (s * NBK + b) * SCAP;
#pragma unroll
        for (int k = 0; k < SPT; ++k) {
            int i = k * 1024 + t;
            rkv[s * SPT + k] = 0xFFFFFFFFu;
            if (i < n) {
                unsigned pack = binned[sb + i];
                unsigned src = pack & 0x3FFFFu;
                int key = ((int)(pack >> 18) << 2) | phase_of(src);
                int r = atomicAdd(&cnt[key], 1);
                srcv[s * SPT + k] = src;
                rkv[s * SPT + k] = ((unsigned)r << 11) | (unsigned)key;
            }
        }
    }
    __syncthreads();

    // exclusive scan of 2048 counts: pair-sum + 1024-lane scan (16 waves)
    int h0 = cnt[2 * t];
    int h1 = cnt[2 * t + 1];
    int p = h0 + h1;
    int lane = t & 63;
    int w = t >> 6;
    int incl = p;
#pragma unroll
    for (int off = 1; off < 64; off <<= 1) {
        int v = __shfl_up(incl, off, 64);
        if (lane >= off) incl += v;
    }
    if (lane == 63) wsum[w] = incl;
    __syncthreads();
    int wbase = 0;
#pragma unroll
    for (int ww = 0; ww < 16; ++ww) wbase += (ww < w) ? wsum[ww] : 0;
    int ex = wbase + incl - p;
    excl[2 * t] = ex;
    excl[2 * t + 1] = ex + h0;
    __syncthreads();

    // scatter into LDS stage (bucket-relative positions)
#pragma unroll
    for (int c = 0; c < NSUB * SPT; ++c) {
        unsigned rk = rkv[c];
        if (rk != 0xFFFFFFFFu) {
            int key = (int)(rk & 0x7FFu);
            int r = (int)(rk >> 11);
            stage[excl[key] + r] = srcv[c];
        }
    }

    // per-node stats (cnt/excl are stable; independent of stage)
    if (t < 512) {
        int g = (b << 9) + t;
        if (g < NN) {
            int c0 = cnt[4 * t];
            int c1 = cnt[4 * t + 1];
            int c2 = cnt[4 * t + 2];
            int c3 = cnt[4 * t + 3];
            int extra = 0;
            for (int k = 0; k < nov; ++k) extra += ((int)(ovf[k] >> 32) == g);
            dinv[g] = rsqrtf((float)(c0 + c1 + c2 + c3 + extra) + 1.0f);
            rsg[g] = b * CCAP + excl[4 * t];                 // csr row start (absolute)
            spl[g] = (unsigned)c0 | ((unsigned)c1 << 8) |
                     ((unsigned)c2 << 16) | ((unsigned)c3 << 24);
        }
    }
    __syncthreads();

    // coalesced uint4 write-out (pad to 16B; garbage pad stays in-bucket)
    int total = excl[2047] + cnt[2047];
    int tot4 = (total + 3) >> 2;
    const uint4* st4 = (const uint4*)stage;
    uint4* csr4 = (uint4*)(csr + (size_t)b * CCAP);
#pragma unroll
    for (int k = 0; k < (CCAP / 4 + 1023) / 1024; ++k) {
        int i4 = k * 1024 + t;
        if (i4 < tot4) csr4[i4] = st4[i4];
    }
}

// xph[s] = fp16(dinv[s]*x[s]) padded to 16 halves (one aligned 32B row).
__global__ void k_prep(const float* __restrict__ x, const float* __restrict__ dinv,
                       __half* __restrict__ xph) {
    int i = blockIdx.x * blockDim.x + threadIdx.x;
    if (i >= NN * 16) return;
    int node = i >> 4;
    int c = i & 15;
    float v = (c < IC) ? dinv[node] * x[node * IC + c] : 0.0f;
    xph[i] = __float2half(v);
}

// Layer-1 aggregation, phases pbase..pbase+1. q2 = bid&1 -> XCD parity
// affinity: each XCD gathers from ONE 1.6MB phase region. partial buffer
// index = q2 (buffer 0 accumulates phases 0+2, buffer 1 phases 1+3).
// acc=1 (second pass) read-modify-writes. 4 lanes per dst node.
__global__ __launch_bounds__(256) void k_agg1(const int* __restrict__ rsg,
                                              const unsigned* __restrict__ spl,
                                              const unsigned* __restrict__ csr,
                                              const __half* __restrict__ xph,
                                              float* __restrict__ partial,
                                              int pbase, int acc) {
    int t = threadIdx.x;
    int q2 = blockIdx.x & 1;
    int ph = pbase + q2;
    int blk = blockIdx.x >> 1;
    int g = t >> 2;
    int qq = t & 3;
    int i = blk * 64 + g;
    unsigned sp = spl[i];
    int c0 = (int)(sp & 255u);
    int c1 = (int)((sp >> 8) & 255u);
    int c2 = (int)((sp >> 16) & 255u);
    int c3 = (int)(sp >> 24);
    int off = (ph > 0 ? c0 : 0) + (ph > 1 ? c1 : 0) + (ph > 2 ? c2 : 0);
    int len = ph == 0 ? c0 : ph == 1 ? c1 : ph == 2 ? c2 : c3;
    int beg = rsg[i] + off;
    int end = beg + len;

    float ax = 0.0f, ay = 0.0f, az = 0.0f, aw = 0.0f;
    int j = beg;
    for (; j + 1 < end; j += 2) {
        int s0 = csr[j];
        int s1 = csr[j + 1];
        uint2 u0 = *(const uint2*)(xph + (size_t)s0 * 16 + 4 * qq);
        uint2 u1 = *(const uint2*)(xph + (size_t)s1 * 16 + 4 * qq);
        float2 f0 = __half22float2(*(__half2*)&u0.x);
        float2 f1 = __half22float2(*(__half2*)&u0.y);
        float2 f2 = __half22float2(*(__half2*)&u1.x);
        float2 f3 = __half22float2(*(__half2*)&u1.y);
        ax += f0.x + f2.x;
        ay += f0.y + f2.y;
        az += f1.x + f3.x;
        aw += f1.y + f3.y;
    }
    if (j < end) {
        int s0 = csr[j];
        uint2 u0 = *(const uint2*)(xph + (size_t)s0 * 16 + 4 * qq);
        float2 f0 = __half22float2(*(__half2*)&u0.x);
        float2 f1 = __half22float2(*(__half2*)&u0.y);
        ax += f0.x;
        ay += f0.y;
        az += f1.x;
        aw += f1.y;
    }
    f4v r = {ax, ay, az, aw};
    float* dst = partial + ((size_t)q2 * NN + i) * 16 + 4 * qq;
    if (acc) {
        f4v o = __builtin_nontemporal_load((const f4v*)dst);  // zero-reuse stream
        r += o;
    }
    __builtin_nontemporal_store(r, (f4v*)dst);
}

// Sum phase partials + self loop + overflow-list fixup, then the fused MLP.
__global__ __launch_bounds__(256) void k_mlp(const float* __restrict__ partial,
                                             const __half* __restrict__ xph,
                                             const int* __restrict__ gcur,
                                             const ull* __restrict__ ovf,
                                             const float* __restrict__ dinv,
                                             const float* __restrict__ W1,
                                             const float* __restrict__ b1,
                                             const float* __restrict__ W2,
                                             const float* __restrict__ b2,
                                             float2* __restrict__ h2bp,
                                             float2* __restrict__ selfout) {
    __shared__ float sW1[IC * HC];
    __shared__ float sb1[HC];
    __shared__ float sW2[HC * OC];
    __shared__ float sb2[OC];
    int t = threadIdx.x;
    if (t < IC * HC) sW1[t] = W1[t];
    if (t < HC) sb1[t] = b1[t];
    if (t < HC * OC) sW2[t] = W2[t];
    if (t < OC) sb2[t] = b2[t];
    __syncthreads();

    int i = blockIdx.x * 256 + t;
    if (i >= NN) return;

    float dv = dinv[i];
    const float4* p0 = (const float4*)(partial + (size_t)i * 16);
    const float4* p1 = (const float4*)(partial + ((size_t)NN + i) * 16);
    const uint2* sp = (const uint2*)(xph + (size_t)i * 16);

    float agg[16];
#pragma unroll
    for (int c4 = 0; c4 < 4; ++c4) {
        float4 a = p0[c4];
        float4 b = p1[c4];
        uint2 u = sp[c4];
        float2 s0 = __half22float2(*(__half2*)&u.x);
        float2 s1 = __half22float2(*(__half2*)&u.y);
        agg[4 * c4 + 0] = a.x + b.x + s0.x;
        agg[4 * c4 + 1] = a.y + b.y + s0.y;
        agg[4 * c4 + 2] = a.z + b.z + s1.x;
        agg[4 * c4 + 3] = a.w + b.w + s1.y;
    }

    // overflow fixup (nov==0 in practice)
    int nov = min(gcur[NSEG * GSTR], OVFCAP);
    for (int k = 0; k < nov; ++k) {
        ull e = ovf[k];
        if ((int)(e >> 32) == i) {
            int s = (int)(e & 0xFFFFFFFFu);
            for (int c = 0; c < IC; ++c)
                agg[c] += __half2float(xph[(size_t)s * 16 + c]);
        }
    }

    float tt[IC];
#pragma unroll
    for (int c = 0; c < IC; ++c) tt[c] = dv * agg[c];

    float r[HC];
#pragma unroll
    for (int f = 0; f < HC; ++f) {
        float a = sb1[f];
#pragma unroll
        for (int c = 0; c < IC; ++c) a = fmaf(tt[c], sW1[c * HC + f], a);
        r[f] = fmaxf(a, 0.0f);
    }

    float o0 = 0.0f, o1 = 0.0f;
#pragma unroll
    for (int f = 0; f < HC; ++f) {
        o0 = fmaf(r[f], sW2[f * OC + 0], o0);
        o1 = fmaf(r[f], sW2[f * OC + 1], o1);
    }
    h2bp[i] = make_float2(o0 * dv, o1 * dv);  // dinv-prescaled for layer 2
    selfout[i] = make_float2(o0 * dv * dv + sb2[0], o1 * dv * dv + sb2[1]);
}

// layer-2: out[i] = selfout[i] + dinv[i] * (sum h2bp[src] + ovf matches).
// 4 lanes per node (stride-4 interleaved walk), 2-way unroll -> short
// dependent chains + plenty of loads in flight; shfl_xor(1,2) combine.
__global__ __launch_bounds__(256) void k_agg2(const int* __restrict__ rsg,
                                              const unsigned* __restrict__ spl,
                                              const unsigned* __restrict__ csr,
                                              const int* __restrict__ gcur,
                                              const ull* __restrict__ ovf,
                                              const float* __restrict__ dinv,
                                              const float2* __restrict__ h2bp,
                                              const float2* __restrict__ selfout,
                                              float2* __restrict__ out) {
    int tt = blockIdx.x * 256 + threadIdx.x;
    int i = tt >> 2;
    int h = tt & 3;
    if (i >= NN) return;
    unsigned sp = spl[i];
    int tot = (int)(sp & 255u) + (int)((sp >> 8) & 255u) +
              (int)((sp >> 16) & 255u) + (int)(sp >> 24);
    int beg = rsg[i];
    int end = beg + tot;
    float ax = 0.0f, ay = 0.0f;
    int j = beg + h;
    for (; j + 4 < end; j += 8) {
        int s0 = csr[j];
        int s1 = csr[j + 4];
        float2 h0 = h2bp[s0];
        float2 h1 = h2bp[s1];
        ax += h0.x + h1.x;
        ay += h0.y + h1.y;
    }
    if (j < end) {
        float2 h0 = h2bp[csr[j]];
        ax += h0.x;
        ay += h0.y;
    }
    ax += __shfl_xor(ax, 1);
    ay += __shfl_xor(ay, 1);
    ax += __shfl_xor(ax, 2);
    ay += __shfl_xor(ay, 2);
    if (h == 0) {
        // overflow fixup (nov==0 in practice); h2bp already dinv[src]-prescaled
        int nov = min(gcur[NSEG * GSTR], OVFCAP);
        for (int k = 0; k < nov; ++k) {
            ull e = ovf[k];
            if ((int)(e >> 32) == i) {
                float2 hh = h2bp[(int)(e & 0xFFFFFFFFu)];
                ax += hh.x;
                ay += hh.y;
            }
        }
        float dv = dinv[i];
        float2 so = selfout[i];
        out[i] = make_float2(so.x + dv * ax, so.y + dv * ay);
    }
}

extern "C" void kernel_launch(void* const* d_in, const int* in_sizes, int n_in,
                              void* d_out, int out_size, void* d_ws, size_t ws_size,
                              hipStream_t stream) {
    const float* x = (const float*)d_in[0];
    const void* ei = d_in[1];
    // d_in[2] = edge_attr (unused)
    const float* W1 = (const float*)d_in[3];
    const float* b1 = (const float*)d_in[4];
    const float* W2 = (const float*)d_in[5];
    const float* b2 = (const float*)d_in[6];
    float* out = (float*)d_out;

    ull* ovf = (ull*)d_ws;                              // OVFCAP       (0.5MB)
    int* gcur = (int*)(ovf + OVFCAP);                   // (NSEG+1)*16 ints (200KB)
    int* flag = gcur + (NSEG + 1) * GSTR;               // 4
    int* rsg = flag + 4;                                // NN
    unsigned* spl = (unsigned*)(rsg + NN);              // NN
    float* dinv = (float*)(spl + NN);                   // NN
    __half* xph = (__half*)(dinv + NN);                 // NN*16 halves (6.4MB)
    float2* h2bp = (float2*)(xph + (size_t)NN * 16);    // NN
    float2* selfout = h2bp + NN;                        // NN
    unsigned* binned = (unsigned*)(selfout + NN);       // NSEG*SCAP    (35.3MB)
    float* partial = (float*)binned;                    // 2*NN*16 f32 (25.6MB), overlays
                                                        // binned (dead after k_sort)
    unsigned* csr = binned + (size_t)NSEG * SCAP;       // NBK*CCAP     (35.3MB)

    k_init<<<(NSEG + 1 + 255) / 256, 256, 0, stream>>>(gcur, ei, flag);
    k_binA<<<NTILE, BTH, 0, stream>>>(ei, flag, gcur, binned, ovf);
    k_sort<<<NBK, 1024, 0, stream>>>(gcur, binned, ovf, csr, dinv, rsg, spl);
    k_prep<<<(NN * 16 + 255) / 256, 256, 0, stream>>>(x, dinv, xph);
    k_agg1<<<2 * NAGG, 256, 0, stream>>>(rsg, spl, csr, xph, partial, 0, 0);
    k_agg1<<<2 * NAGG, 256, 0, stream>>>(rsg, spl, csr, xph, partial, 2, 1);
    k_mlp<<<NB, 256, 0, stream>>>(partial, xph, gcur, ovf, dinv, W1, b1, W2, b2,
                                  h2bp, selfout);
    k_agg2<<<(NN * 4 + 255) / 256, 256, 0, stream>>>(rsg, spl, csr, gcur, ovf, dinv,
                                                     h2bp, selfout, (float2*)out);
}